// Round 3
// baseline (477.234 us; speedup 1.0000x reference)
//
#include <hip/hip_runtime.h>
#include <math.h>

#define B_  4
#define S_  2048
#define D_  1024
#define H_  16
#define DH_ 64
#define M_  (B_*S_)

typedef unsigned short ushort_t;
typedef __attribute__((ext_vector_type(8))) __bf16 bf16x8;
typedef __attribute__((ext_vector_type(4))) float f32x4;
typedef __attribute__((ext_vector_type(8))) unsigned short us8;
typedef __attribute__((ext_vector_type(4))) unsigned short us4;

__device__ __forceinline__ ushort_t f2bf(float f) {
    unsigned int u = __float_as_uint(f);
    u = (u + 0x7fffu + ((u >> 16) & 1u)) >> 16;   // RNE
    return (ushort_t)u;
}

// async global->LDS, 16B per lane, wave-uniform LDS base (HW: base + lane*16)
#define GLD16(gp, lp) __builtin_amdgcn_global_load_lds( \
    (const __attribute__((address_space(1))) void*)(gp), \
    (__attribute__((address_space(3))) void*)(lp), 16, 0, 0)

#define WAIT_VM0()   __builtin_amdgcn_s_waitcnt(0x0F70)  // vmcnt(0) only
#define WAIT_VM4()   __builtin_amdgcn_s_waitcnt(0x0F74)  // vmcnt(4) only
#define WAIT_LGKM0() __builtin_amdgcn_s_waitcnt(0xC07F)  // lgkmcnt(0) only
#define MEMFENCE()   asm volatile("" ::: "memory")

// ---------------------------------------------------------------------------
// fp32 -> bf16 converters
// ---------------------------------------------------------------------------
__global__ __launch_bounds__(256)
void cvt_kernel(const float* __restrict__ src, ushort_t* __restrict__ dst, int n)
{
    int i = (blockIdx.x * 256 + threadIdx.x) * 8;
    if (i >= n) return;
    float4 a = *(const float4*)(src + i);
    float4 b = *(const float4*)(src + i + 4);
    us8 r;
    r[0] = f2bf(a.x); r[1] = f2bf(a.y); r[2] = f2bf(a.z); r[3] = f2bf(a.w);
    r[4] = f2bf(b.x); r[5] = f2bf(b.y); r[6] = f2bf(b.z); r[7] = f2bf(b.w);
    *(us8*)(dst + i) = r;
}

__global__ __launch_bounds__(256)
void cvt_w4(const float* __restrict__ w0, const float* __restrict__ w1,
            const float* __restrict__ w2, const float* __restrict__ w3,
            ushort_t* __restrict__ dst)
{
    const int ten = blockIdx.y;
    const float* s = (ten == 0) ? w0 : (ten == 1) ? w1 : (ten == 2) ? w2 : w3;
    ushort_t* d = dst + (size_t)ten * (D_ * D_);
    int i = (blockIdx.x * 256 + threadIdx.x) * 8;
    float4 a = *(const float4*)(s + i);
    float4 b = *(const float4*)(s + i + 4);
    us8 r;
    r[0] = f2bf(a.x); r[1] = f2bf(a.y); r[2] = f2bf(a.z); r[3] = f2bf(a.w);
    r[4] = f2bf(b.x); r[5] = f2bf(b.y); r[6] = f2bf(b.z); r[7] = f2bf(b.w);
    *(us8*)(d + i) = r;
}

// ---------------------------------------------------------------------------
// MFMA GEMM: Y = A @ Bw^T + bias.  A:[M,K] bf16, Bw:[N,K] bf16 (torch weight).
// 128x128 tile, BK=32, 256 thr = 4 waves (2x2), 4x4 16x16x32 MFMAs per wave.
// mode 0: N=3072 fused QKV -> scatter Q(bf16,*0.125)/K(bf16)/V^T(bf16)
// mode 1: N=1024 -> fp32 Yf[m*1024+n]
// ---------------------------------------------------------------------------
__global__ __launch_bounds__(256)
void gemm_mfma(const ushort_t* __restrict__ A, const ushort_t* __restrict__ Bw,
               const float* __restrict__ bias0, const float* __restrict__ bias1,
               const float* __restrict__ bias2,
               float* __restrict__ Yf, ushort_t* __restrict__ Qo,
               ushort_t* __restrict__ Ko, ushort_t* __restrict__ Vo,
               int K, int mode)
{
    __shared__ __align__(16) ushort_t As[128 * 32];
    __shared__ __align__(16) ushort_t Bs[128 * 32];
    const int t = threadIdx.x;
    const int lane = t & 63, wave = t >> 6;
    const int wm = wave >> 1, wn = wave & 1;
    const int m0 = blockIdx.x * 128, n0 = blockIdx.y * 128;
    const int quad = lane >> 4, l15 = lane & 15;

    const int ch0 = wave * 2, ch1 = wave * 2 + 1;
    const int srow = lane >> 2;          // 0..15
    const int scol = (lane & 3) * 8;     // 0,8,16,24
    const ushort_t* Ap0 = A  + (size_t)(m0 + ch0 * 16 + srow) * K + scol;
    const ushort_t* Ap1 = A  + (size_t)(m0 + ch1 * 16 + srow) * K + scol;
    const ushort_t* Bp0 = Bw + (size_t)(n0 + ch0 * 16 + srow) * K + scol;
    const ushort_t* Bp1 = Bw + (size_t)(n0 + ch1 * 16 + srow) * K + scol;
    ushort_t* lA0 = As + ch0 * 512;
    ushort_t* lA1 = As + ch1 * 512;
    ushort_t* lB0 = Bs + ch0 * 512;
    ushort_t* lB1 = Bs + ch1 * 512;

    f32x4 acc[4][4] = {};

    for (int k0 = 0; k0 < K; k0 += 32) {
        GLD16(Ap0 + k0, lA0);
        GLD16(Ap1 + k0, lA1);
        GLD16(Bp0 + k0, lB0);
        GLD16(Bp1 + k0, lB1);
        WAIT_VM0();
        __syncthreads();

        bf16x8 af[4], bfr[4];
        #pragma unroll
        for (int i = 0; i < 4; i++)
            af[i] = *(const bf16x8*)(As + (64 * wm + 16 * i + l15) * 32 + quad * 8);
        #pragma unroll
        for (int j = 0; j < 4; j++)
            bfr[j] = *(const bf16x8*)(Bs + (64 * wn + 16 * j + l15) * 32 + quad * 8);
        #pragma unroll
        for (int i = 0; i < 4; i++)
            #pragma unroll
            for (int j = 0; j < 4; j++)
                acc[i][j] = __builtin_amdgcn_mfma_f32_16x16x32_bf16(af[i], bfr[j], acc[i][j], 0, 0, 0);
        __syncthreads();
    }

    // epilogue — C/D layout: row = quad*4+r, col = l15
    #pragma unroll
    for (int j = 0; j < 4; j++) {
        const int n = n0 + 64 * wn + 16 * j + l15;
        if (mode == 1) {
            const float bv = bias0[n];
            #pragma unroll
            for (int i = 0; i < 4; i++) {
                const int mrow = m0 + 64 * wm + 16 * i + quad * 4;
                float* yp = Yf + (size_t)mrow * D_ + n;
                #pragma unroll
                for (int r = 0; r < 4; r++)
                    yp[(size_t)r * D_] = acc[i][j][r] + bv;
            }
        } else {
            const int sel = n >> 10, nn = n & 1023;
            const int hh = nn >> 6, dd = nn & 63;
            const float bv = (sel == 0 ? bias0 : (sel == 1 ? bias1 : bias2))[nn];
            const float scl = (sel == 0) ? 0.125f : 1.0f;
            #pragma unroll
            for (int i = 0; i < 4; i++) {
                const int mrow = m0 + 64 * wm + 16 * i + quad * 4;
                const int b = mrow >> 11;
                const int ss = mrow & (S_ - 1);
                #pragma unroll
                for (int r = 0; r < 4; r++) {
                    const float v = (acc[i][j][r] + bv) * scl;
                    const ushort_t bvv = f2bf(v);
                    if (sel == 0)
                        Qo[(((size_t)b * H_ + hh) * S_ + ss + r) * DH_ + dd] = bvv;
                    else if (sel == 1)
                        Ko[(((size_t)b * H_ + hh) * S_ + ss + r) * DH_ + dd] = bvv;
                    else
                        Vo[(((size_t)b * H_ + hh) * DH_ + dd) * S_ + ss + r] = bvv;
                }
            }
        }
    }
}

// ---------------------------------------------------------------------------
// MFMA flash attention (causal).  Qb/Kb: [B,H,S,64] bf16 (Q pre-scaled 1/8),
// Vt: [B,H,64,S] bf16.  out: [B,S,D] fp32.
// Q-tile 128 (wave w owns rows 32w..32w+31 as two 16-row frag groups),
// K-tile 64, double-buffered LDS staging with raw s_barrier + manual vmcnt
// so next tile's global_load_lds stays in flight across the barrier.
// ---------------------------------------------------------------------------
__global__ __launch_bounds__(256)
void attn_mfma(const ushort_t* __restrict__ Qb, const ushort_t* __restrict__ Kb,
               const ushort_t* __restrict__ Vt, float* __restrict__ out)
{
    __shared__ __align__(16) ushort_t Ks[2][64 * 64];
    __shared__ __align__(16) ushort_t Vs[2][64 * 64];
    __shared__ __align__(16) ushort_t Ps[4][32 * 72];
    const int t = threadIdx.x, lane = t & 63, w = t >> 6;
    const int qt = (int)gridDim.x - 1 - (int)blockIdx.x;   // big tiles first
    const int bh = blockIdx.y;
    const int q0 = qt * 128;
    const int quad = lane >> 4, l15 = lane & 15;
    const int rw = 32 * w;                 // wave's first row within q-tile

    // Q A-frags (layout: m=l15, k=quad*8+j), two 16-row groups g=0,1
    const ushort_t* qp = Qb + ((size_t)bh * S_ + q0 + rw + l15) * DH_;
    bf16x8 fq[2][2];
    fq[0][0] = *(const bf16x8*)(qp + quad * 8);
    fq[0][1] = *(const bf16x8*)(qp + 32 + quad * 8);
    fq[1][0] = *(const bf16x8*)(qp + 16 * DH_ + quad * 8);
    fq[1][1] = *(const bf16x8*)(qp + 16 * DH_ + 32 + quad * 8);

    f32x4 o[2][4] = {};
    float m_i[2][4], l_i[2][4];
    #pragma unroll
    for (int g = 0; g < 2; g++)
        #pragma unroll
        for (int r = 0; r < 4; r++) { m_i[g][r] = -INFINITY; l_i[g][r] = 0.f; }

    // staging: 8 K-chunks + 8 V-chunks of 1KB; wave w stages chunks 2w,2w+1
    const int c0 = 2 * w, c1 = 2 * w + 1;
    const int srow = lane >> 3;                   // 0..7 row within chunk
    const int scol = 8 * ((lane & 7) ^ srow);     // XOR-8 swizzled column
    const ushort_t* Kg0 = Kb + ((size_t)bh * S_ + c0 * 8 + srow) * DH_ + scol;
    const ushort_t* Kg1 = Kb + ((size_t)bh * S_ + c1 * 8 + srow) * DH_ + scol;
    const ushort_t* Vg0 = Vt + ((size_t)bh * DH_ + c0 * 8 + srow) * S_ + scol;
    const ushort_t* Vg1 = Vt + ((size_t)bh * DH_ + c1 * 8 + srow) * S_ + scol;
    ushort_t* pw = Ps[w];

    WAIT_VM0();          // Q frags resident -> manual vmcnt bookkeeping is exact
    MEMFENCE();

    // prefetch tile 0 into buffer 0
    GLD16(Kg0, &Ks[0][c0 * 512]);
    GLD16(Kg1, &Ks[0][c1 * 512]);
    GLD16(Vg0, &Vs[0][c0 * 512]);
    GLD16(Vg1, &Vs[0][c1 * 512]);

    const int last = 2 * qt + 1;
    for (int kt = 0; kt <= last; kt++) {
        const int buf = kt & 1;
        const int k0 = kt * 64;
        if (kt < last) {
            const size_t ko = (size_t)(k0 + 64) * DH_;
            GLD16(Kg0 + ko, &Ks[buf ^ 1][c0 * 512]);
            GLD16(Kg1 + ko, &Ks[buf ^ 1][c1 * 512]);
            GLD16(Vg0 + k0 + 64, &Vs[buf ^ 1][c0 * 512]);
            GLD16(Vg1 + k0 + 64, &Vs[buf ^ 1][c1 * 512]);
            WAIT_VM4();          // oldest 4 (current tile) landed; new 4 in flight
        } else {
            WAIT_VM0();
        }
        MEMFENCE();
        __builtin_amdgcn_s_barrier();
        MEMFENCE();

        if (k0 <= q0 + rw + 31) {   // wave not fully masked for this k-tile
            const ushort_t* kb = Ks[buf];
            f32x4 sc[2][4] = {};
            #pragma unroll
            for (int ct = 0; ct < 4; ct++) {
                const int n = ct * 16 + l15;
                const int sw = 8 * (n & 7);
                const bf16x8 b0 = *(const bf16x8*)(kb + n * 64 + ((quad * 8) ^ sw));
                const bf16x8 b1 = *(const bf16x8*)(kb + n * 64 + ((32 + quad * 8) ^ sw));
                sc[0][ct] = __builtin_amdgcn_mfma_f32_16x16x32_bf16(fq[0][0], b0, sc[0][ct], 0, 0, 0);
                sc[0][ct] = __builtin_amdgcn_mfma_f32_16x16x32_bf16(fq[0][1], b1, sc[0][ct], 0, 0, 0);
                sc[1][ct] = __builtin_amdgcn_mfma_f32_16x16x32_bf16(fq[1][0], b0, sc[1][ct], 0, 0, 0);
                sc[1][ct] = __builtin_amdgcn_mfma_f32_16x16x32_bf16(fq[1][1], b1, sc[1][ct], 0, 0, 0);
            }

            #pragma unroll
            for (int g = 0; g < 2; g++) {
                const int rowg = q0 + rw + 16 * g + quad * 4;
                if (k0 + 63 > rowg) {               // diagonal band: causal mask
                    #pragma unroll
                    for (int ct = 0; ct < 4; ct++) {
                        const int key = k0 + ct * 16 + l15;
                        #pragma unroll
                        for (int r = 0; r < 4; r++)
                            if (key > rowg + r) sc[g][ct][r] = -INFINITY;
                    }
                }
            }

            #pragma unroll
            for (int g = 0; g < 2; g++) {
                float vr[4];
                #pragma unroll
                for (int r = 0; r < 4; r++)
                    vr[r] = fmaxf(fmaxf(sc[g][0][r], sc[g][1][r]),
                                  fmaxf(sc[g][2][r], sc[g][3][r]));
                #pragma unroll
                for (int off = 1; off < 16; off <<= 1)
                    #pragma unroll
                    for (int r = 0; r < 4; r++)
                        vr[r] = fmaxf(vr[r], __shfl_xor(vr[r], off));

                float alpha[4], rs[4];
                #pragma unroll
                for (int r = 0; r < 4; r++) {
                    const float mn = fmaxf(m_i[g][r], vr[r]);
                    alpha[r] = __expf(m_i[g][r] - mn);
                    m_i[g][r] = mn;
                    rs[r] = 0.f;
                }
                #pragma unroll
                for (int ct = 0; ct < 4; ct++)
                    #pragma unroll
                    for (int r = 0; r < 4; r++) {
                        const float p = __expf(sc[g][ct][r] - m_i[g][r]);
                        rs[r] += p;
                        pw[(16 * g + quad * 4 + r) * 72 + ct * 16 + l15] = f2bf(p);
                    }
                #pragma unroll
                for (int off = 1; off < 16; off <<= 1)
                    #pragma unroll
                    for (int r = 0; r < 4; r++)
                        rs[r] += __shfl_xor(rs[r], off);
                #pragma unroll
                for (int r = 0; r < 4; r++)
                    l_i[g][r] = l_i[g][r] * alpha[r] + rs[r];
                #pragma unroll
                for (int jt = 0; jt < 4; jt++)
                    #pragma unroll
                    for (int r = 0; r < 4; r++)
                        o[g][jt][r] *= alpha[r];
            }

            // O += P V   (P LDS round-trip is per-wave: no barrier needed)
            WAIT_LGKM0();
            MEMFENCE();
            bf16x8 pf[2][2];
            #pragma unroll
            for (int g = 0; g < 2; g++) {
                pf[g][0] = *(const bf16x8*)(pw + (16 * g + l15) * 72 + quad * 8);
                pf[g][1] = *(const bf16x8*)(pw + (16 * g + l15) * 72 + 32 + quad * 8);
            }
            const ushort_t* vb = Vs[buf];
            #pragma unroll
            for (int jt = 0; jt < 4; jt++) {
                const int n = jt * 16 + l15;
                const int sw = 8 * (n & 7);
                const bf16x8 v0 = *(const bf16x8*)(vb + n * 64 + ((quad * 8) ^ sw));
                const bf16x8 v1 = *(const bf16x8*)(vb + n * 64 + ((32 + quad * 8) ^ sw));
                o[0][jt] = __builtin_amdgcn_mfma_f32_16x16x32_bf16(pf[0][0], v0, o[0][jt], 0, 0, 0);
                o[0][jt] = __builtin_amdgcn_mfma_f32_16x16x32_bf16(pf[0][1], v1, o[0][jt], 0, 0, 0);
                o[1][jt] = __builtin_amdgcn_mfma_f32_16x16x32_bf16(pf[1][0], v0, o[1][jt], 0, 0, 0);
                o[1][jt] = __builtin_amdgcn_mfma_f32_16x16x32_bf16(pf[1][1], v1, o[1][jt], 0, 0, 0);
            }
        }
        MEMFENCE();
        __builtin_amdgcn_s_barrier();    // all reads of buf done before overwrite
        MEMFENCE();
    }

    const int b = bh >> 4, h = bh & (H_ - 1);
    #pragma unroll
    for (int g = 0; g < 2; g++)
        #pragma unroll
        for (int jt = 0; jt < 4; jt++)
            #pragma unroll
            for (int r = 0; r < 4; r++) {
                const int sg = q0 + rw + 16 * g + quad * 4 + r;
                out[((size_t)(b * S_ + sg)) * D_ + h * DH_ + jt * 16 + l15] =
                    o[g][jt][r] / l_i[g][r];
            }
}

// ---------------------------------------------------------------------------
// out = LayerNorm(A + R) * g + b ; optional bf16 copy of out
// ---------------------------------------------------------------------------
__global__ __launch_bounds__(256)
void add_ln_kernel(const float* __restrict__ A, const float* __restrict__ R,
                   const float* __restrict__ g, const float* __restrict__ bia,
                   float* __restrict__ out, ushort_t* __restrict__ out_bf)
{
    const int row = blockIdx.x;
    const int t   = threadIdx.x;
    const float4 av = ((const float4*)(A + (size_t)row * D_))[t];
    const float4 rv = ((const float4*)(R + (size_t)row * D_))[t];
    float4 s;
    s.x = av.x + rv.x; s.y = av.y + rv.y; s.z = av.z + rv.z; s.w = av.w + rv.w;

    float sum = s.x + s.y + s.z + s.w;
    float sq  = s.x*s.x + s.y*s.y + s.z*s.z + s.w*s.w;
    #pragma unroll
    for (int off = 32; off > 0; off >>= 1) {
        sum += __shfl_down(sum, off);
        sq  += __shfl_down(sq,  off);
    }
    __shared__ float wsum[4], wsq[4], stat[2];
    const int wid = t >> 6, lane = t & 63;
    if (lane == 0) { wsum[wid] = sum; wsq[wid] = sq; }
    __syncthreads();
    if (t == 0) {
        float S = wsum[0] + wsum[1] + wsum[2] + wsum[3];
        float Q = wsq[0]  + wsq[1]  + wsq[2]  + wsq[3];
        float mean = S * (1.0f / D_);
        float var  = Q * (1.0f / D_) - mean * mean;
        stat[0] = mean;
        stat[1] = rsqrtf(var + 1e-5f);
    }
    __syncthreads();
    const float mean = stat[0], inv = stat[1];
    const float4 gv = ((const float4*)g)[t];
    const float4 bv = ((const float4*)bia)[t];
    float4 o;
    o.x = (s.x - mean) * inv * gv.x + bv.x;
    o.y = (s.y - mean) * inv * gv.y + bv.y;
    o.z = (s.z - mean) * inv * gv.z + bv.z;
    o.w = (s.w - mean) * inv * gv.w + bv.w;
    ((float4*)(out + (size_t)row * D_))[t] = o;
    if (out_bf) {
        us4 ob;
        ob[0] = f2bf(o.x); ob[1] = f2bf(o.y); ob[2] = f2bf(o.z); ob[3] = f2bf(o.w);
        *(us4*)(out_bf + (size_t)row * D_ + t * 4) = ob;
    }
}

// ---------------------------------------------------------------------------
extern "C" void kernel_launch(void* const* d_in, const int* in_sizes, int n_in,
                              void* d_out, int out_size, void* d_ws, size_t ws_size,
                              hipStream_t stream)
{
    const float* x      = (const float*)d_in[0];
    const float* wq_w   = (const float*)d_in[1];
    const float* wq_b   = (const float*)d_in[2];
    const float* wk_w   = (const float*)d_in[3];
    const float* wk_b   = (const float*)d_in[4];
    const float* wv_w   = (const float*)d_in[5];
    const float* wv_b   = (const float*)d_in[6];
    const float* ln1_g  = (const float*)d_in[7];
    const float* ln1_b  = (const float*)d_in[8];
    const float* lin1_w = (const float*)d_in[9];
    const float* lin1_b = (const float*)d_in[10];
    const float* ln2_g  = (const float*)d_in[11];
    const float* ln2_b  = (const float*)d_in[12];
    float* out = (float*)d_out;

    char* base = (char*)d_ws;
    ushort_t* x_bf = (ushort_t*)(base);
    ushort_t* w_bf = (ushort_t*)(base + 16777216);
    ushort_t* Qbf  = (ushort_t*)(base + 25165824);
    ushort_t* Kbf  = (ushort_t*)(base + 41943040);
    ushort_t* Vtp  = (ushort_t*)(base + 58720256);
    float*    h    = (float*)   (base + 25165824);
    ushort_t* h_bf = (ushort_t*)(base + 58720256);

    cvt_kernel<<<dim3((M_ * D_) / 2048), 256, 0, stream>>>(x, x_bf, M_ * D_);
    cvt_w4<<<dim3((D_ * D_) / 2048, 4), 256, 0, stream>>>(wq_w, wk_w, wv_w, lin1_w, w_bf);

    gemm_mfma<<<dim3(M_ / 128, 3072 / 128), 256, 0, stream>>>(
        x_bf, w_bf, wq_b, wk_b, wv_b, nullptr, Qbf, Kbf, Vtp, D_, 0);

    attn_mfma<<<dim3(S_ / 128, B_ * H_), 256, 0, stream>>>(Qbf, Kbf, Vtp, out);

    add_ln_kernel<<<M_, 256, 0, stream>>>(x, out, ln1_g, ln1_b, h, h_bf);

    gemm_mfma<<<dim3(M_ / 128, D_ / 128), 256, 0, stream>>>(
        h_bf, w_bf + 3 * D_ * D_, lin1_b, nullptr, nullptr, out, nullptr, nullptr, nullptr, D_, 1);

    add_ln_kernel<<<M_, 256, 0, stream>>>(h, out, ln2_g, ln2_b, out, nullptr);
}

// Round 5
// 396.625 us; speedup vs baseline: 1.2032x; 1.2032x over previous
//
#include <hip/hip_runtime.h>
#include <math.h>

#define B_  4
#define S_  2048
#define D_  1024
#define H_  16
#define DH_ 64
#define M_  (B_*S_)

typedef unsigned short ushort_t;
typedef __attribute__((ext_vector_type(8))) __bf16 bf16x8;
typedef __attribute__((ext_vector_type(4))) float f32x4;
typedef __attribute__((ext_vector_type(8))) unsigned short us8;
typedef __attribute__((ext_vector_type(4))) unsigned short us4;

__device__ __forceinline__ ushort_t f2bf(float f) {
    unsigned int u = __float_as_uint(f);
    u = (u + 0x7fffu + ((u >> 16) & 1u)) >> 16;   // RNE
    return (ushort_t)u;
}

// async global->LDS, 16B per lane, wave-uniform LDS base (HW: base + lane*16)
#define GLD16(gp, lp) __builtin_amdgcn_global_load_lds( \
    (const __attribute__((address_space(1))) void*)(gp), \
    (__attribute__((address_space(3))) void*)(lp), 16, 0, 0)

#define WAIT_VM0()   __builtin_amdgcn_s_waitcnt(0x0F70)  // vmcnt(0) only
#define WAIT_VM4()   __builtin_amdgcn_s_waitcnt(0x0F74)  // vmcnt(4) only
#define WAIT_LGKM0() __builtin_amdgcn_s_waitcnt(0xC07F)  // lgkmcnt(0) only
#define MEMFENCE()   asm volatile("" ::: "memory")

// ---------------------------------------------------------------------------
// fp32 -> bf16 converters
// ---------------------------------------------------------------------------
__global__ __launch_bounds__(256)
void cvt_kernel(const float* __restrict__ src, ushort_t* __restrict__ dst, int n)
{
    int i = (blockIdx.x * 256 + threadIdx.x) * 8;
    if (i >= n) return;
    float4 a = *(const float4*)(src + i);
    float4 b = *(const float4*)(src + i + 4);
    us8 r;
    r[0] = f2bf(a.x); r[1] = f2bf(a.y); r[2] = f2bf(a.z); r[3] = f2bf(a.w);
    r[4] = f2bf(b.x); r[5] = f2bf(b.y); r[6] = f2bf(b.z); r[7] = f2bf(b.w);
    *(us8*)(dst + i) = r;
}

__global__ __launch_bounds__(256)
void cvt_w4(const float* __restrict__ w0, const float* __restrict__ w1,
            const float* __restrict__ w2, const float* __restrict__ w3,
            ushort_t* __restrict__ dst)
{
    const int ten = blockIdx.y;
    const float* s = (ten == 0) ? w0 : (ten == 1) ? w1 : (ten == 2) ? w2 : w3;
    ushort_t* d = dst + (size_t)ten * (D_ * D_);
    int i = (blockIdx.x * 256 + threadIdx.x) * 8;
    float4 a = *(const float4*)(s + i);
    float4 b = *(const float4*)(s + i + 4);
    us8 r;
    r[0] = f2bf(a.x); r[1] = f2bf(a.y); r[2] = f2bf(a.z); r[3] = f2bf(a.w);
    r[4] = f2bf(b.x); r[5] = f2bf(b.y); r[6] = f2bf(b.z); r[7] = f2bf(b.w);
    *(us8*)(d + i) = r;
}

// ---------------------------------------------------------------------------
// MFMA GEMM: Y = A @ Bw^T + bias.  A:[M,K] bf16, Bw:[N,K] bf16 (torch weight).
// 128x128 tile, BK=32, 256 thr = 4 waves (2x2), 4x4 16x16x32 MFMAs per wave.
// mode 0: N=3072 fused QKV -> scatter Q(bf16,*0.125)/K(bf16)/V^T(bf16)
// mode 1: N=1024 -> fp32 Yf[m*1024+n]
// ---------------------------------------------------------------------------
__global__ __launch_bounds__(256)
void gemm_mfma(const ushort_t* __restrict__ A, const ushort_t* __restrict__ Bw,
               const float* __restrict__ bias0, const float* __restrict__ bias1,
               const float* __restrict__ bias2,
               float* __restrict__ Yf, ushort_t* __restrict__ Qo,
               ushort_t* __restrict__ Ko, ushort_t* __restrict__ Vo,
               int K, int mode)
{
    __shared__ __align__(16) ushort_t As[128 * 32];
    __shared__ __align__(16) ushort_t Bs[128 * 32];
    const int t = threadIdx.x;
    const int lane = t & 63, wave = t >> 6;
    const int wm = wave >> 1, wn = wave & 1;
    const int m0 = blockIdx.x * 128, n0 = blockIdx.y * 128;
    const int quad = lane >> 4, l15 = lane & 15;

    const int ch0 = wave * 2, ch1 = wave * 2 + 1;
    const int srow = lane >> 2;          // 0..15
    const int scol = (lane & 3) * 8;     // 0,8,16,24
    const ushort_t* Ap0 = A  + (size_t)(m0 + ch0 * 16 + srow) * K + scol;
    const ushort_t* Ap1 = A  + (size_t)(m0 + ch1 * 16 + srow) * K + scol;
    const ushort_t* Bp0 = Bw + (size_t)(n0 + ch0 * 16 + srow) * K + scol;
    const ushort_t* Bp1 = Bw + (size_t)(n0 + ch1 * 16 + srow) * K + scol;
    ushort_t* lA0 = As + ch0 * 512;
    ushort_t* lA1 = As + ch1 * 512;
    ushort_t* lB0 = Bs + ch0 * 512;
    ushort_t* lB1 = Bs + ch1 * 512;

    f32x4 acc[4][4] = {};

    for (int k0 = 0; k0 < K; k0 += 32) {
        GLD16(Ap0 + k0, lA0);
        GLD16(Ap1 + k0, lA1);
        GLD16(Bp0 + k0, lB0);
        GLD16(Bp1 + k0, lB1);
        WAIT_VM0();
        __syncthreads();

        bf16x8 af[4], bfr[4];
        #pragma unroll
        for (int i = 0; i < 4; i++)
            af[i] = *(const bf16x8*)(As + (64 * wm + 16 * i + l15) * 32 + quad * 8);
        #pragma unroll
        for (int j = 0; j < 4; j++)
            bfr[j] = *(const bf16x8*)(Bs + (64 * wn + 16 * j + l15) * 32 + quad * 8);
        #pragma unroll
        for (int i = 0; i < 4; i++)
            #pragma unroll
            for (int j = 0; j < 4; j++)
                acc[i][j] = __builtin_amdgcn_mfma_f32_16x16x32_bf16(af[i], bfr[j], acc[i][j], 0, 0, 0);
        __syncthreads();
    }

    // epilogue — C/D layout: row = quad*4+r, col = l15
    #pragma unroll
    for (int j = 0; j < 4; j++) {
        const int n = n0 + 64 * wn + 16 * j + l15;
        if (mode == 1) {
            const float bv = bias0[n];
            #pragma unroll
            for (int i = 0; i < 4; i++) {
                const int mrow = m0 + 64 * wm + 16 * i + quad * 4;
                float* yp = Yf + (size_t)mrow * D_ + n;
                #pragma unroll
                for (int r = 0; r < 4; r++)
                    yp[(size_t)r * D_] = acc[i][j][r] + bv;
            }
        } else {
            const int sel = n >> 10, nn = n & 1023;
            const int hh = nn >> 6, dd = nn & 63;
            const float bv = (sel == 0 ? bias0 : (sel == 1 ? bias1 : bias2))[nn];
            const float scl = (sel == 0) ? 0.125f : 1.0f;
            #pragma unroll
            for (int i = 0; i < 4; i++) {
                const int mrow = m0 + 64 * wm + 16 * i + quad * 4;
                const int b = mrow >> 11;
                const int ss = mrow & (S_ - 1);
                #pragma unroll
                for (int r = 0; r < 4; r++) {
                    const float v = (acc[i][j][r] + bv) * scl;
                    const ushort_t bvv = f2bf(v);
                    if (sel == 0)
                        Qo[(((size_t)b * H_ + hh) * S_ + ss + r) * DH_ + dd] = bvv;
                    else if (sel == 1)
                        Ko[(((size_t)b * H_ + hh) * S_ + ss + r) * DH_ + dd] = bvv;
                    else
                        Vo[(((size_t)b * H_ + hh) * DH_ + dd) * S_ + ss + r] = bvv;
                }
            }
        }
    }
}

// ---------------------------------------------------------------------------
// MFMA flash attention (causal), TRANSPOSED-score formulation.
//   S^T = K·Q^T  (C/D: row=key=quad*4+r, col=query=l15)
//   O^T = V^T·P^T (A-frag = V^T from Vt staging; B-frag = P rows from LDS)
// Per-lane softmax: 15 in-register ops + 2 shfl_xor (quads) per reduction.
// Qb/Kb: [B,H,S,64] bf16 (Q pre-scaled 1/8), Vt: [B,H,64,S] bf16.
// Q-tile 128: wave w owns queries 32w..32w+31 (two 16-query groups).
// K/V double-buffered via global_load_lds + raw s_barrier + manual vmcnt.
// ---------------------------------------------------------------------------
__global__ __launch_bounds__(256, 3)
void attn_mfma(const ushort_t* __restrict__ Qb, const ushort_t* __restrict__ Kb,
               const ushort_t* __restrict__ Vt, float* __restrict__ out)
{
    // K tile: [key 0..63][dh 0..63], 16B-unit col swizzle c8' = c8 ^ (row&7)
    // V^T tile: [dh 0..63][key 0..63], same swizzle
    __shared__ __align__(16) ushort_t Ks[2][64 * 64];
    __shared__ __align__(16) ushort_t Vs[2][64 * 64];
    __shared__ __align__(16) ushort_t Ps[4][16 * 72];   // per-wave P [16q][64k], stride 72
    const int t = threadIdx.x, lane = t & 63, w = t >> 6;
    const int qt = (int)gridDim.x - 1 - (int)blockIdx.x;   // big tiles first
    const int bh = blockIdx.y;
    const int q0 = qt * 128;
    const int quad = lane >> 4, l15 = lane & 15;
    const int rw = 32 * w;                 // wave's first query within q-tile

    // Q B-frags (n=query=l15, k=dh=quad*8+j), groups g=0,1, dh-halves h=0,1
    const ushort_t* qp = Qb + ((size_t)bh * S_ + q0 + rw + l15) * DH_ + quad * 8;
    bf16x8 qf[2][2];
    qf[0][0] = *(const bf16x8*)(qp);
    qf[0][1] = *(const bf16x8*)(qp + 32);
    qf[1][0] = *(const bf16x8*)(qp + 16 * DH_);
    qf[1][1] = *(const bf16x8*)(qp + 16 * DH_ + 32);

    f32x4 o[2][4] = {};                    // O^T: [g][mt], dh=mt*16+quad*4+r, q=l15
    float m_i[2] = { -INFINITY, -INFINITY }, l_i[2] = { 0.f, 0.f };

    // staging: 8 K-chunks + 8 V-chunks of 1KB; wave w stages chunks 2w,2w+1
    const int c0 = 2 * w, c1 = 2 * w + 1;
    const int srow = lane >> 3;                   // 0..7 row within chunk
    const int scol = 8 * ((lane & 7) ^ srow);     // XOR-8 swizzled col (ushort)
    const ushort_t* Kg0 = Kb + ((size_t)bh * S_ + c0 * 8 + srow) * DH_ + scol;
    const ushort_t* Kg1 = Kb + ((size_t)bh * S_ + c1 * 8 + srow) * DH_ + scol;
    const ushort_t* Vg0 = Vt + ((size_t)bh * DH_ + c0 * 8 + srow) * S_ + scol;
    const ushort_t* Vg1 = Vt + ((size_t)bh * DH_ + c1 * 8 + srow) * S_ + scol;
    ushort_t* pw = Ps[w];

    WAIT_VM0();          // Q frags resident -> manual vmcnt bookkeeping is exact
    MEMFENCE();

    // prefetch tile 0 into buffer 0
    GLD16(Kg0, &Ks[0][c0 * 512]);
    GLD16(Kg1, &Ks[0][c1 * 512]);
    GLD16(Vg0, &Vs[0][c0 * 512]);
    GLD16(Vg1, &Vs[0][c1 * 512]);

    const int last = 2 * qt + 1;
    for (int kt = 0; kt <= last; kt++) {
        const int buf = kt & 1;
        const int k0 = kt * 64;
        if (kt < last) {
            const size_t ko = (size_t)(k0 + 64) * DH_;
            GLD16(Kg0 + ko, &Ks[buf ^ 1][c0 * 512]);
            GLD16(Kg1 + ko, &Ks[buf ^ 1][c1 * 512]);
            GLD16(Vg0 + k0 + 64, &Vs[buf ^ 1][c0 * 512]);
            GLD16(Vg1 + k0 + 64, &Vs[buf ^ 1][c1 * 512]);
            WAIT_VM4();          // own prev-tile loads landed; barrier certifies all
        } else {
            WAIT_VM0();
        }
        MEMFENCE();
        __builtin_amdgcn_s_barrier();
        MEMFENCE();

        if (k0 <= q0 + rw + 31) {          // wave has at least one unmasked query
            const ushort_t* kb = Ks[buf];
            const ushort_t* vb = Vs[buf];
            const int xr = l15 & 7;        // swizzle term (row&7) for frag reads

            // K A-frags: m=key=ct*16+l15, k=dh=h*32+quad*8+j
            bf16x8 kf[4][2];
            #pragma unroll
            for (int ct = 0; ct < 4; ct++)
                #pragma unroll
                for (int h = 0; h < 2; h++)
                    kf[ct][h] = *(const bf16x8*)(kb + (ct * 16 + l15) * 64 +
                                                 8 * ((h * 4 + quad) ^ xr));
            // V^T A-frags: m=dh=mt*16+l15, k=key=h*32+quad*8+j
            bf16x8 vf[4][2];
            #pragma unroll
            for (int mt = 0; mt < 4; mt++)
                #pragma unroll
                for (int h = 0; h < 2; h++)
                    vf[mt][h] = *(const bf16x8*)(vb + (mt * 16 + l15) * 64 +
                                                 8 * ((h * 4 + quad) ^ xr));

            #pragma unroll
            for (int g = 0; g < 2; g++) {
                const int qg0 = q0 + rw + 16 * g;      // group's first query
                if (k0 > qg0 + 15) continue;           // fully masked for group

                // ---- S^T tile: key=k0+ct*16+quad*4+r, query=qg0+l15 ----
                f32x4 sc[4] = {};
                #pragma unroll
                for (int ct = 0; ct < 4; ct++) {
                    sc[ct] = __builtin_amdgcn_mfma_f32_16x16x32_bf16(kf[ct][0], qf[g][0], sc[ct], 0, 0, 0);
                    sc[ct] = __builtin_amdgcn_mfma_f32_16x16x32_bf16(kf[ct][1], qf[g][1], sc[ct], 0, 0, 0);
                }
                if (k0 + 63 > qg0) {                   // diagonal band: mask
                    const int qq = qg0 + l15;
                    #pragma unroll
                    for (int ct = 0; ct < 4; ct++) {
                        const int key = k0 + ct * 16 + quad * 4;
                        #pragma unroll
                        for (int r = 0; r < 4; r++)
                            if (key + r > qq) sc[ct][r] = -INFINITY;
                    }
                }

                // ---- per-lane softmax (all 16 regs share query=l15) ----
                float mx = sc[0][0];
                #pragma unroll
                for (int ct = 0; ct < 4; ct++)
                    #pragma unroll
                    for (int r = 0; r < 4; r++) mx = fmaxf(mx, sc[ct][r]);
                mx = fmaxf(mx, __shfl_xor(mx, 16));
                mx = fmaxf(mx, __shfl_xor(mx, 32));

                const float mn = fmaxf(m_i[g], mx);
                const float alpha = __expf(m_i[g] - mn);
                m_i[g] = mn;

                float rs = 0.f;
                #pragma unroll
                for (int ct = 0; ct < 4; ct++) {
                    us4 pk;
                    #pragma unroll
                    for (int r = 0; r < 4; r++) {
                        const float p = __expf(sc[ct][r] - mn);
                        rs += p;
                        pk[r] = f2bf(p);
                    }
                    // P[query=l15][key=ct*16+quad*4 .. +3]
                    *(us4*)(pw + l15 * 72 + ct * 16 + quad * 4) = pk;
                }
                rs += __shfl_xor(rs, 16);
                rs += __shfl_xor(rs, 32);
                l_i[g] = l_i[g] * alpha + rs;

                #pragma unroll
                for (int mt = 0; mt < 4; mt++)
                    #pragma unroll
                    for (int r = 0; r < 4; r++) o[g][mt][r] *= alpha;

                // ---- O^T += V^T · P^T ----
                // B-frag of P^T: n=query=l15, k=key=h*32+quad*8+j
                WAIT_LGKM0();
                MEMFENCE();
                bf16x8 pf[2];
                pf[0] = *(const bf16x8*)(pw + l15 * 72 + quad * 8);        // keys 0..31
                pf[1] = *(const bf16x8*)(pw + l15 * 72 + 32 + quad * 8);   // keys 32..63
                #pragma unroll
                for (int mt = 0; mt < 4; mt++) {
                    o[g][mt] = __builtin_amdgcn_mfma_f32_16x16x32_bf16(vf[mt][0], pf[0], o[g][mt], 0, 0, 0);
                    o[g][mt] = __builtin_amdgcn_mfma_f32_16x16x32_bf16(vf[mt][1], pf[1], o[g][mt], 0, 0, 0);
                }
            }
        }
        MEMFENCE();
        __builtin_amdgcn_s_barrier();    // all reads of buf done before overwrite
        MEMFENCE();
    }

    const int b = bh >> 4, h = bh & (H_ - 1);
    #pragma unroll
    for (int g = 0; g < 2; g++) {
        const float inv = 1.0f / l_i[g];
        const int query = q0 + rw + 16 * g + l15;
        float* ob = out + ((size_t)(b * S_ + query)) * D_ + h * DH_ + quad * 4;
        #pragma unroll
        for (int mt = 0; mt < 4; mt++) {
            float4 rv;
            rv.x = o[g][mt][0] * inv; rv.y = o[g][mt][1] * inv;
            rv.z = o[g][mt][2] * inv; rv.w = o[g][mt][3] * inv;
            *(float4*)(ob + mt * 16) = rv;
        }
    }
}

// ---------------------------------------------------------------------------
// out = LayerNorm(A + R) * g + b ; optional bf16 copy of out
// ---------------------------------------------------------------------------
__global__ __launch_bounds__(256)
void add_ln_kernel(const float* __restrict__ A, const float* __restrict__ R,
                   const float* __restrict__ g, const float* __restrict__ bia,
                   float* __restrict__ out, ushort_t* __restrict__ out_bf)
{
    const int row = blockIdx.x;
    const int t   = threadIdx.x;
    const float4 av = ((const float4*)(A + (size_t)row * D_))[t];
    const float4 rv = ((const float4*)(R + (size_t)row * D_))[t];
    float4 s;
    s.x = av.x + rv.x; s.y = av.y + rv.y; s.z = av.z + rv.z; s.w = av.w + rv.w;

    float sum = s.x + s.y + s.z + s.w;
    float sq  = s.x*s.x + s.y*s.y + s.z*s.z + s.w*s.w;
    #pragma unroll
    for (int off = 32; off > 0; off >>= 1) {
        sum += __shfl_down(sum, off);
        sq  += __shfl_down(sq,  off);
    }
    __shared__ float wsum[4], wsq[4], stat[2];
    const int wid = t >> 6, lane = t & 63;
    if (lane == 0) { wsum[wid] = sum; wsq[wid] = sq; }
    __syncthreads();
    if (t == 0) {
        float S = wsum[0] + wsum[1] + wsum[2] + wsum[3];
        float Q = wsq[0]  + wsq[1]  + wsq[2]  + wsq[3];
        float mean = S * (1.0f / D_);
        float var  = Q * (1.0f / D_) - mean * mean;
        stat[0] = mean;
        stat[1] = rsqrtf(var + 1e-5f);
    }
    __syncthreads();
    const float mean = stat[0], inv = stat[1];
    const float4 gv = ((const float4*)g)[t];
    const float4 bv = ((const float4*)bia)[t];
    float4 o;
    o.x = (s.x - mean) * inv * gv.x + bv.x;
    o.y = (s.y - mean) * inv * gv.y + bv.y;
    o.z = (s.z - mean) * inv * gv.z + bv.z;
    o.w = (s.w - mean) * inv * gv.w + bv.w;
    ((float4*)(out + (size_t)row * D_))[t] = o;
    if (out_bf) {
        us4 ob;
        ob[0] = f2bf(o.x); ob[1] = f2bf(o.y); ob[2] = f2bf(o.z); ob[3] = f2bf(o.w);
        *(us4*)(out_bf + (size_t)row * D_ + t * 4) = ob;
    }
}

// ---------------------------------------------------------------------------
extern "C" void kernel_launch(void* const* d_in, const int* in_sizes, int n_in,
                              void* d_out, int out_size, void* d_ws, size_t ws_size,
                              hipStream_t stream)
{
    const float* x      = (const float*)d_in[0];
    const float* wq_w   = (const float*)d_in[1];
    const float* wq_b   = (const float*)d_in[2];
    const float* wk_w   = (const float*)d_in[3];
    const float* wk_b   = (const float*)d_in[4];
    const float* wv_w   = (const float*)d_in[5];
    const float* wv_b   = (const float*)d_in[6];
    const float* ln1_g  = (const float*)d_in[7];
    const float* ln1_b  = (const float*)d_in[8];
    const float* lin1_w = (const float*)d_in[9];
    const float* lin1_b = (const float*)d_in[10];
    const float* ln2_g  = (const float*)d_in[11];
    const float* ln2_b  = (const float*)d_in[12];
    float* out = (float*)d_out;

    char* base = (char*)d_ws;
    ushort_t* x_bf = (ushort_t*)(base);
    ushort_t* w_bf = (ushort_t*)(base + 16777216);
    ushort_t* Qbf  = (ushort_t*)(base + 25165824);
    ushort_t* Kbf  = (ushort_t*)(base + 41943040);
    ushort_t* Vtp  = (ushort_t*)(base + 58720256);
    float*    h    = (float*)   (base + 25165824);
    ushort_t* h_bf = (ushort_t*)(base + 58720256);

    cvt_kernel<<<dim3((M_ * D_) / 2048), 256, 0, stream>>>(x, x_bf, M_ * D_);
    cvt_w4<<<dim3((D_ * D_) / 2048, 4), 256, 0, stream>>>(wq_w, wk_w, wv_w, lin1_w, w_bf);

    gemm_mfma<<<dim3(M_ / 128, 3072 / 128), 256, 0, stream>>>(
        x_bf, w_bf, wq_b, wk_b, wv_b, nullptr, Qbf, Kbf, Vtp, D_, 0);

    attn_mfma<<<dim3(S_ / 128, B_ * H_), 256, 0, stream>>>(Qbf, Kbf, Vtp, out);

    add_ln_kernel<<<M_, 256, 0, stream>>>(x, out, ln1_g, ln1_b, h, h_bf);

    gemm_mfma<<<dim3(M_ / 128, D_ / 128), 256, 0, stream>>>(
        h_bf, w_bf + 3 * D_ * D_, lin1_b, nullptr, nullptr, out, nullptr, nullptr, nullptr, D_, 1);

    add_ln_kernel<<<M_, 256, 0, stream>>>(h, out, ln2_g, ln2_b, out, nullptr);
}

// Round 6
// 345.332 us; speedup vs baseline: 1.3820x; 1.1485x over previous
//
#include <hip/hip_runtime.h>
#include <math.h>

#define B_  4
#define S_  2048
#define D_  1024
#define H_  16
#define DH_ 64
#define M_  (B_*S_)

typedef unsigned short ushort_t;
typedef __attribute__((ext_vector_type(8))) __bf16 bf16x8;
typedef __attribute__((ext_vector_type(4))) float f32x4;
typedef __attribute__((ext_vector_type(8))) unsigned short us8;
typedef __attribute__((ext_vector_type(4))) unsigned short us4;

__device__ __forceinline__ ushort_t f2bf(float f) {
    unsigned int u = __float_as_uint(f);
    u = (u + 0x7fffu + ((u >> 16) & 1u)) >> 16;   // RNE
    return (ushort_t)u;
}

// async global->LDS, 16B per lane, wave-uniform LDS base (HW: base + lane*16)
#define GLD16(gp, lp) __builtin_amdgcn_global_load_lds( \
    (const __attribute__((address_space(1))) void*)(gp), \
    (__attribute__((address_space(3))) void*)(lp), 16, 0, 0)

#define WAIT_VM0()   __builtin_amdgcn_s_waitcnt(0x0F70)  // vmcnt(0) only
#define WAIT_VM4()   __builtin_amdgcn_s_waitcnt(0x0F74)  // vmcnt(4) only
#define MEMFENCE()   asm volatile("" ::: "memory")

// ---------------------------------------------------------------------------
// fp32 -> bf16 converters
// ---------------------------------------------------------------------------
__global__ __launch_bounds__(256)
void cvt_kernel(const float* __restrict__ src, ushort_t* __restrict__ dst, int n)
{
    int i = (blockIdx.x * 256 + threadIdx.x) * 8;
    if (i >= n) return;
    float4 a = *(const float4*)(src + i);
    float4 b = *(const float4*)(src + i + 4);
    us8 r;
    r[0] = f2bf(a.x); r[1] = f2bf(a.y); r[2] = f2bf(a.z); r[3] = f2bf(a.w);
    r[4] = f2bf(b.x); r[5] = f2bf(b.y); r[6] = f2bf(b.z); r[7] = f2bf(b.w);
    *(us8*)(dst + i) = r;
}

__global__ __launch_bounds__(256)
void cvt_w4(const float* __restrict__ w0, const float* __restrict__ w1,
            const float* __restrict__ w2, const float* __restrict__ w3,
            ushort_t* __restrict__ dst)
{
    const int ten = blockIdx.y;
    const float* s = (ten == 0) ? w0 : (ten == 1) ? w1 : (ten == 2) ? w2 : w3;
    ushort_t* d = dst + (size_t)ten * (D_ * D_);
    int i = (blockIdx.x * 256 + threadIdx.x) * 8;
    float4 a = *(const float4*)(s + i);
    float4 b = *(const float4*)(s + i + 4);
    us8 r;
    r[0] = f2bf(a.x); r[1] = f2bf(a.y); r[2] = f2bf(a.z); r[3] = f2bf(a.w);
    r[4] = f2bf(b.x); r[5] = f2bf(b.y); r[6] = f2bf(b.z); r[7] = f2bf(b.w);
    *(us8*)(d + i) = r;
}

// ---------------------------------------------------------------------------
// MFMA GEMM: Y = A @ Bw^T + bias.  A:[M,K] bf16, Bw:[N,K] bf16 (torch weight).
// 128x128 tile, BK=32, 256 thr = 4 waves (2x2), 4x4 16x16x32 MFMAs per wave.
// mode 0: N=3072 fused QKV -> scatter Q(bf16,*0.125)/K(bf16)/V^T(bf16)
// mode 1: N=1024 -> fp32 Yf[m*1024+n]
// ---------------------------------------------------------------------------
__global__ __launch_bounds__(256)
void gemm_mfma(const ushort_t* __restrict__ A, const ushort_t* __restrict__ Bw,
               const float* __restrict__ bias0, const float* __restrict__ bias1,
               const float* __restrict__ bias2,
               float* __restrict__ Yf, ushort_t* __restrict__ Qo,
               ushort_t* __restrict__ Ko, ushort_t* __restrict__ Vo,
               int K, int mode)
{
    __shared__ __align__(16) ushort_t As[128 * 32];
    __shared__ __align__(16) ushort_t Bs[128 * 32];
    const int t = threadIdx.x;
    const int lane = t & 63, wave = t >> 6;
    const int wm = wave >> 1, wn = wave & 1;
    const int m0 = blockIdx.x * 128, n0 = blockIdx.y * 128;
    const int quad = lane >> 4, l15 = lane & 15;

    const int ch0 = wave * 2, ch1 = wave * 2 + 1;
    const int srow = lane >> 2;          // 0..15
    const int scol = (lane & 3) * 8;     // 0,8,16,24
    const ushort_t* Ap0 = A  + (size_t)(m0 + ch0 * 16 + srow) * K + scol;
    const ushort_t* Ap1 = A  + (size_t)(m0 + ch1 * 16 + srow) * K + scol;
    const ushort_t* Bp0 = Bw + (size_t)(n0 + ch0 * 16 + srow) * K + scol;
    const ushort_t* Bp1 = Bw + (size_t)(n0 + ch1 * 16 + srow) * K + scol;
    ushort_t* lA0 = As + ch0 * 512;
    ushort_t* lA1 = As + ch1 * 512;
    ushort_t* lB0 = Bs + ch0 * 512;
    ushort_t* lB1 = Bs + ch1 * 512;

    f32x4 acc[4][4] = {};

    for (int k0 = 0; k0 < K; k0 += 32) {
        GLD16(Ap0 + k0, lA0);
        GLD16(Ap1 + k0, lA1);
        GLD16(Bp0 + k0, lB0);
        GLD16(Bp1 + k0, lB1);
        WAIT_VM0();
        __syncthreads();

        bf16x8 af[4], bfr[4];
        #pragma unroll
        for (int i = 0; i < 4; i++)
            af[i] = *(const bf16x8*)(As + (64 * wm + 16 * i + l15) * 32 + quad * 8);
        #pragma unroll
        for (int j = 0; j < 4; j++)
            bfr[j] = *(const bf16x8*)(Bs + (64 * wn + 16 * j + l15) * 32 + quad * 8);
        #pragma unroll
        for (int i = 0; i < 4; i++)
            #pragma unroll
            for (int j = 0; j < 4; j++)
                acc[i][j] = __builtin_amdgcn_mfma_f32_16x16x32_bf16(af[i], bfr[j], acc[i][j], 0, 0, 0);
        __syncthreads();
    }

    // epilogue — C/D layout: row = quad*4+r, col = l15
    #pragma unroll
    for (int j = 0; j < 4; j++) {
        const int n = n0 + 64 * wn + 16 * j + l15;
        if (mode == 1) {
            const float bv = bias0[n];
            #pragma unroll
            for (int i = 0; i < 4; i++) {
                const int mrow = m0 + 64 * wm + 16 * i + quad * 4;
                float* yp = Yf + (size_t)mrow * D_ + n;
                #pragma unroll
                for (int r = 0; r < 4; r++)
                    yp[(size_t)r * D_] = acc[i][j][r] + bv;
            }
        } else {
            const int sel = n >> 10, nn = n & 1023;
            const int hh = nn >> 6, dd = nn & 63;
            const float bv = (sel == 0 ? bias0 : (sel == 1 ? bias1 : bias2))[nn];
            const float scl = (sel == 0) ? 0.125f : 1.0f;
            #pragma unroll
            for (int i = 0; i < 4; i++) {
                const int mrow = m0 + 64 * wm + 16 * i + quad * 4;
                const int b = mrow >> 11;
                const int ss = mrow & (S_ - 1);
                #pragma unroll
                for (int r = 0; r < 4; r++) {
                    const float v = (acc[i][j][r] + bv) * scl;
                    const ushort_t bvv = f2bf(v);
                    if (sel == 0)
                        Qo[(((size_t)b * H_ + hh) * S_ + ss + r) * DH_ + dd] = bvv;
                    else if (sel == 1)
                        Ko[(((size_t)b * H_ + hh) * S_ + ss + r) * DH_ + dd] = bvv;
                    else
                        Vo[(((size_t)b * H_ + hh) * DH_ + dd) * S_ + ss + r] = bvv;
                }
            }
        }
    }
}

// ---------------------------------------------------------------------------
// MFMA flash attention (causal), transposed-score formulation.
//   S^T = K·Q^T  (C/D: row=key=quad*4+r, col=query=l15)
//   O^T = V^T·P^T
// Equal-work pairing: block bx in [0,8) runs q-tiles {15-bx, bx} -> every
// block does exactly 34 k-iterations; grid 512 = 2 blocks/CU uniformly.
// Per-(wave,g) P buffers so the two 16-query chains overlap (ILP 2).
// K/V double-buffered via global_load_lds + raw s_barrier + manual vmcnt.
// ---------------------------------------------------------------------------
__global__ __launch_bounds__(256, 2)
void attn_mfma(const ushort_t* __restrict__ Qb, const ushort_t* __restrict__ Kb,
               const ushort_t* __restrict__ Vt, float* __restrict__ out)
{
    __shared__ __align__(16) ushort_t Ks[2][64 * 64];
    __shared__ __align__(16) ushort_t Vs[2][64 * 64];
    __shared__ __align__(16) ushort_t Ps[8][16 * 72];   // [wave*2+g][16q][64k+pad]
    const int t = threadIdx.x, lane = t & 63, w = t >> 6;
    const int bx = blockIdx.x;             // 0..7
    const int bh = blockIdx.y;
    const int quad = lane >> 4, l15 = lane & 15;
    const int rw = 32 * w;                 // wave's first query within q-tile

    // staging geometry (fixed): 8 K-chunks + 8 V-chunks of 1KB; wave w: 2w,2w+1
    const int c0 = 2 * w, c1 = 2 * w + 1;
    const int srow = lane >> 3;                   // 0..7 row within chunk
    const int scol = 8 * ((lane & 7) ^ srow);     // XOR-8 swizzled col (ushort)
    const ushort_t* KgB = Kb + (size_t)bh * S_ * DH_;
    const ushort_t* VgB = Vt + (size_t)bh * DH_ * S_;
    const ushort_t* Kg0 = KgB + (size_t)(c0 * 8 + srow) * DH_ + scol;
    const ushort_t* Kg1 = KgB + (size_t)(c1 * 8 + srow) * DH_ + scol;
    const ushort_t* Vg0 = VgB + (size_t)(c0 * 8 + srow) * S_ + scol;
    const ushort_t* Vg1 = VgB + (size_t)(c1 * 8 + srow) * S_ + scol;
    ushort_t* pw0 = Ps[w * 2 + 0];
    ushort_t* pw1 = Ps[w * 2 + 1];
    const int b = bh >> 4, hh = bh & (H_ - 1);

    for (int ph = 0; ph < 2; ph++) {
        const int qt = ph ? bx : (15 - bx);
        const int q0 = qt * 128;

        // Q B-frags (n=query=l15, k=dh=quad*8+j); groups g=0,1; dh-halves 0,1
        const ushort_t* qp = Qb + ((size_t)bh * S_ + q0 + rw + l15) * DH_ + quad * 8;
        const bf16x8 qf00 = *(const bf16x8*)(qp);
        const bf16x8 qf01 = *(const bf16x8*)(qp + 32);
        const bf16x8 qf10 = *(const bf16x8*)(qp + 16 * DH_);
        const bf16x8 qf11 = *(const bf16x8*)(qp + 16 * DH_ + 32);

        f32x4 o0[4] = {}, o1[4] = {};
        float m0v = -INFINITY, m1v = -INFINITY, l0v = 0.f, l1v = 0.f;

        WAIT_VM0();      // Q frags resident; vmcnt bookkeeping exact from here
        MEMFENCE();
        GLD16(Kg0, &Ks[0][c0 * 512]);
        GLD16(Kg1, &Ks[0][c1 * 512]);
        GLD16(Vg0, &Vs[0][c0 * 512]);
        GLD16(Vg1, &Vs[0][c1 * 512]);

        const int qg00 = q0 + rw;          // g=0 first query
        const int qg10 = q0 + rw + 16;     // g=1 first query
        const int last = 2 * qt + 1;

        for (int kt = 0; kt <= last; kt++) {
            const int buf = kt & 1;
            const int k0 = kt * 64;
            if (kt < last) {
                const size_t ko = (size_t)(k0 + 64) * DH_;
                GLD16(Kg0 + ko, &Ks[buf ^ 1][c0 * 512]);
                GLD16(Kg1 + ko, &Ks[buf ^ 1][c1 * 512]);
                GLD16(Vg0 + k0 + 64, &Vs[buf ^ 1][c0 * 512]);
                GLD16(Vg1 + k0 + 64, &Vs[buf ^ 1][c1 * 512]);
                WAIT_VM4();      // own prev-tile chunks landed; barrier certifies all
            } else {
                WAIT_VM0();
            }
            MEMFENCE();
            __builtin_amdgcn_s_barrier();
            MEMFENCE();

            if (k0 <= qg10 + 15) {         // wave has at least one unmasked query
                const bool a0 = (k0 <= qg00 + 15);
                const ushort_t* kb = Ks[buf];
                const ushort_t* vb = Vs[buf];
                const int xr = l15 & 7;    // swizzle term (row&7) for frag reads

                // K A-frags: m=key=ct*16+l15, k=dh=h*32+quad*8+j
                bf16x8 kf[4][2];
                #pragma unroll
                for (int ct = 0; ct < 4; ct++)
                    #pragma unroll
                    for (int h = 0; h < 2; h++)
                        kf[ct][h] = *(const bf16x8*)(kb + (ct * 16 + l15) * 64 +
                                                     8 * ((h * 4 + quad) ^ xr));

                // ---- S^T tiles, both groups ----
                f32x4 sc0[4] = {}, sc1[4] = {};
                #pragma unroll
                for (int ct = 0; ct < 4; ct++) {
                    sc1[ct] = __builtin_amdgcn_mfma_f32_16x16x32_bf16(kf[ct][0], qf10, sc1[ct], 0, 0, 0);
                    sc1[ct] = __builtin_amdgcn_mfma_f32_16x16x32_bf16(kf[ct][1], qf11, sc1[ct], 0, 0, 0);
                }
                if (a0) {
                    #pragma unroll
                    for (int ct = 0; ct < 4; ct++) {
                        sc0[ct] = __builtin_amdgcn_mfma_f32_16x16x32_bf16(kf[ct][0], qf00, sc0[ct], 0, 0, 0);
                        sc0[ct] = __builtin_amdgcn_mfma_f32_16x16x32_bf16(kf[ct][1], qf01, sc0[ct], 0, 0, 0);
                    }
                }

                // V^T A-frags: m=dh=mt*16+l15, k=key=h*32+quad*8+j
                bf16x8 vf[4][2];
                #pragma unroll
                for (int mt = 0; mt < 4; mt++)
                    #pragma unroll
                    for (int h = 0; h < 2; h++)
                        vf[mt][h] = *(const bf16x8*)(vb + (mt * 16 + l15) * 64 +
                                                     8 * ((h * 4 + quad) ^ xr));

                // ---- causal masking (diagonal band) ----
                if (k0 + 63 > qg10) {
                    const int qq = qg10 + l15;
                    #pragma unroll
                    for (int ct = 0; ct < 4; ct++) {
                        const int key = k0 + ct * 16 + quad * 4;
                        #pragma unroll
                        for (int r = 0; r < 4; r++)
                            if (key + r > qq) sc1[ct][r] = -INFINITY;
                    }
                }
                if (a0 && k0 + 63 > qg00) {
                    const int qq = qg00 + l15;
                    #pragma unroll
                    for (int ct = 0; ct < 4; ct++) {
                        const int key = k0 + ct * 16 + quad * 4;
                        #pragma unroll
                        for (int r = 0; r < 4; r++)
                            if (key + r > qq) sc0[ct][r] = -INFINITY;
                    }
                }

                // ---- per-lane softmax, both groups interleaved ----
                float mx0 = -INFINITY, mx1 = sc1[0][0];
                #pragma unroll
                for (int ct = 0; ct < 4; ct++)
                    #pragma unroll
                    for (int r = 0; r < 4; r++) mx1 = fmaxf(mx1, sc1[ct][r]);
                if (a0) {
                    mx0 = sc0[0][0];
                    #pragma unroll
                    for (int ct = 0; ct < 4; ct++)
                        #pragma unroll
                        for (int r = 0; r < 4; r++) mx0 = fmaxf(mx0, sc0[ct][r]);
                }
                mx1 = fmaxf(mx1, __shfl_xor(mx1, 16));
                mx0 = fmaxf(mx0, __shfl_xor(mx0, 16));
                mx1 = fmaxf(mx1, __shfl_xor(mx1, 32));
                mx0 = fmaxf(mx0, __shfl_xor(mx0, 32));

                const float mn1 = fmaxf(m1v, mx1);
                const float al1 = __expf(m1v - mn1);
                m1v = mn1;
                const float mn0 = a0 ? fmaxf(m0v, mx0) : m0v;
                const float al0 = a0 ? __expf(m0v - mn0) : 1.f;
                m0v = mn0;

                float rs0 = 0.f, rs1 = 0.f;
                #pragma unroll
                for (int ct = 0; ct < 4; ct++) {
                    us4 pk;
                    #pragma unroll
                    for (int r = 0; r < 4; r++) {
                        const float p = __expf(sc1[ct][r] - mn1);
                        rs1 += p;
                        pk[r] = f2bf(p);
                    }
                    *(us4*)(pw1 + l15 * 72 + ct * 16 + quad * 4) = pk;
                }
                if (a0) {
                    #pragma unroll
                    for (int ct = 0; ct < 4; ct++) {
                        us4 pk;
                        #pragma unroll
                        for (int r = 0; r < 4; r++) {
                            const float p = __expf(sc0[ct][r] - mn0);
                            rs0 += p;
                            pk[r] = f2bf(p);
                        }
                        *(us4*)(pw0 + l15 * 72 + ct * 16 + quad * 4) = pk;
                    }
                }
                rs1 += __shfl_xor(rs1, 16);
                rs0 += __shfl_xor(rs0, 16);
                rs1 += __shfl_xor(rs1, 32);
                rs0 += __shfl_xor(rs0, 32);
                l1v = l1v * al1 + rs1;
                if (a0) l0v = l0v * al0 + rs0;

                #pragma unroll
                for (int mt = 0; mt < 4; mt++)
                    #pragma unroll
                    for (int r = 0; r < 4; r++) { o1[mt][r] *= al1; o0[mt][r] *= al0; }

                // ---- O^T += V^T · P^T  (B-frag: n=query=l15, k=key=h*32+quad*8+j)
                const bf16x8 pf10 = *(const bf16x8*)(pw1 + l15 * 72 + quad * 8);
                const bf16x8 pf11 = *(const bf16x8*)(pw1 + l15 * 72 + 32 + quad * 8);
                #pragma unroll
                for (int mt = 0; mt < 4; mt++) {
                    o1[mt] = __builtin_amdgcn_mfma_f32_16x16x32_bf16(vf[mt][0], pf10, o1[mt], 0, 0, 0);
                    o1[mt] = __builtin_amdgcn_mfma_f32_16x16x32_bf16(vf[mt][1], pf11, o1[mt], 0, 0, 0);
                }
                if (a0) {
                    const bf16x8 pf00 = *(const bf16x8*)(pw0 + l15 * 72 + quad * 8);
                    const bf16x8 pf01 = *(const bf16x8*)(pw0 + l15 * 72 + 32 + quad * 8);
                    #pragma unroll
                    for (int mt = 0; mt < 4; mt++) {
                        o0[mt] = __builtin_amdgcn_mfma_f32_16x16x32_bf16(vf[mt][0], pf00, o0[mt], 0, 0, 0);
                        o0[mt] = __builtin_amdgcn_mfma_f32_16x16x32_bf16(vf[mt][1], pf01, o0[mt], 0, 0, 0);
                    }
                }
            }
            MEMFENCE();
            __builtin_amdgcn_s_barrier();    // all reads of buf done before overwrite
            MEMFENCE();
        }

        // epilogue: O^T lane layout dh=mt*16+quad*4+r, query=l15
        {
            const float inv0 = 1.0f / l0v, inv1 = 1.0f / l1v;
            const int query0 = q0 + rw + l15;
            float* ob0 = out + ((size_t)(b * S_ + query0)) * D_ + hh * DH_ + quad * 4;
            float* ob1 = ob0 + (size_t)16 * D_;
            #pragma unroll
            for (int mt = 0; mt < 4; mt++) {
                float4 r0, r1;
                r0.x = o0[mt][0] * inv0; r0.y = o0[mt][1] * inv0;
                r0.z = o0[mt][2] * inv0; r0.w = o0[mt][3] * inv0;
                r1.x = o1[mt][0] * inv1; r1.y = o1[mt][1] * inv1;
                r1.z = o1[mt][2] * inv1; r1.w = o1[mt][3] * inv1;
                *(float4*)(ob0 + mt * 16) = r0;
                *(float4*)(ob1 + mt * 16) = r1;
            }
        }
    }
}

// ---------------------------------------------------------------------------
// out = LayerNorm(A + R) * g + b ; optional bf16 copy of out
// ---------------------------------------------------------------------------
__global__ __launch_bounds__(256)
void add_ln_kernel(const float* __restrict__ A, const float* __restrict__ R,
                   const float* __restrict__ g, const float* __restrict__ bia,
                   float* __restrict__ out, ushort_t* __restrict__ out_bf)
{
    const int row = blockIdx.x;
    const int t   = threadIdx.x;
    const float4 av = ((const float4*)(A + (size_t)row * D_))[t];
    const float4 rv = ((const float4*)(R + (size_t)row * D_))[t];
    float4 s;
    s.x = av.x + rv.x; s.y = av.y + rv.y; s.z = av.z + rv.z; s.w = av.w + rv.w;

    float sum = s.x + s.y + s.z + s.w;
    float sq  = s.x*s.x + s.y*s.y + s.z*s.z + s.w*s.w;
    #pragma unroll
    for (int off = 32; off > 0; off >>= 1) {
        sum += __shfl_down(sum, off);
        sq  += __shfl_down(sq,  off);
    }
    __shared__ float wsum[4], wsq[4], stat[2];
    const int wid = t >> 6, lane = t & 63;
    if (lane == 0) { wsum[wid] = sum; wsq[wid] = sq; }
    __syncthreads();
    if (t == 0) {
        float S = wsum[0] + wsum[1] + wsum[2] + wsum[3];
        float Q = wsq[0]  + wsq[1]  + wsq[2]  + wsq[3];
        float mean = S * (1.0f / D_);
        float var  = Q * (1.0f / D_) - mean * mean;
        stat[0] = mean;
        stat[1] = rsqrtf(var + 1e-5f);
    }
    __syncthreads();
    const float mean = stat[0], inv = stat[1];
    const float4 gv = ((const float4*)g)[t];
    const float4 bv = ((const float4*)bia)[t];
    float4 o;
    o.x = (s.x - mean) * inv * gv.x + bv.x;
    o.y = (s.y - mean) * inv * gv.y + bv.y;
    o.z = (s.z - mean) * inv * gv.z + bv.z;
    o.w = (s.w - mean) * inv * gv.w + bv.w;
    ((float4*)(out + (size_t)row * D_))[t] = o;
    if (out_bf) {
        us4 ob;
        ob[0] = f2bf(o.x); ob[1] = f2bf(o.y); ob[2] = f2bf(o.z); ob[3] = f2bf(o.w);
        *(us4*)(out_bf + (size_t)row * D_ + t * 4) = ob;
    }
}

// ---------------------------------------------------------------------------
extern "C" void kernel_launch(void* const* d_in, const int* in_sizes, int n_in,
                              void* d_out, int out_size, void* d_ws, size_t ws_size,
                              hipStream_t stream)
{
    const float* x      = (const float*)d_in[0];
    const float* wq_w   = (const float*)d_in[1];
    const float* wq_b   = (const float*)d_in[2];
    const float* wk_w   = (const float*)d_in[3];
    const float* wk_b   = (const float*)d_in[4];
    const float* wv_w   = (const float*)d_in[5];
    const float* wv_b   = (const float*)d_in[6];
    const float* ln1_g  = (const float*)d_in[7];
    const float* ln1_b  = (const float*)d_in[8];
    const float* lin1_w = (const float*)d_in[9];
    const float* lin1_b = (const float*)d_in[10];
    const float* ln2_g  = (const float*)d_in[11];
    const float* ln2_b  = (const float*)d_in[12];
    float* out = (float*)d_out;

    char* base = (char*)d_ws;
    ushort_t* x_bf = (ushort_t*)(base);
    ushort_t* w_bf = (ushort_t*)(base + 16777216);
    ushort_t* Qbf  = (ushort_t*)(base + 25165824);
    ushort_t* Kbf  = (ushort_t*)(base + 41943040);
    ushort_t* Vtp  = (ushort_t*)(base + 58720256);
    float*    h    = (float*)   (base + 25165824);
    ushort_t* h_bf = (ushort_t*)(base + 58720256);

    cvt_kernel<<<dim3((M_ * D_) / 2048), 256, 0, stream>>>(x, x_bf, M_ * D_);
    cvt_w4<<<dim3((D_ * D_) / 2048, 4), 256, 0, stream>>>(wq_w, wk_w, wv_w, lin1_w, w_bf);

    gemm_mfma<<<dim3(M_ / 128, 3072 / 128), 256, 0, stream>>>(
        x_bf, w_bf, wq_b, wk_b, wv_b, nullptr, Qbf, Kbf, Vtp, D_, 0);

    attn_mfma<<<dim3(8, B_ * H_), 256, 0, stream>>>(Qbf, Kbf, Vtp, out);

    add_ln_kernel<<<M_, 256, 0, stream>>>(x, out, ln1_g, ln1_b, h, h_bf);

    gemm_mfma<<<dim3(M_ / 128, D_ / 128), 256, 0, stream>>>(
        h_bf, w_bf + 3 * D_ * D_, lin1_b, nullptr, nullptr, out, nullptr, nullptr, nullptr, D_, 1);

    add_ln_kernel<<<M_, 256, 0, stream>>>(h, out, ln2_g, ln2_b, out, nullptr);
}

// Round 7
// 325.820 us; speedup vs baseline: 1.4647x; 1.0599x over previous
//
#include <hip/hip_runtime.h>
#include <math.h>

#define B_  4
#define S_  2048
#define D_  1024
#define H_  16
#define DH_ 64
#define M_  (B_*S_)

typedef unsigned short ushort_t;
typedef __attribute__((ext_vector_type(8))) __bf16 bf16x8;
typedef __attribute__((ext_vector_type(4))) float f32x4;
typedef __attribute__((ext_vector_type(8))) unsigned short us8;
typedef __attribute__((ext_vector_type(4))) unsigned short us4;

__device__ __forceinline__ ushort_t f2bf(float f) {
    unsigned int u = __float_as_uint(f);
    u = (u + 0x7fffu + ((u >> 16) & 1u)) >> 16;   // RNE
    return (ushort_t)u;
}
__device__ __forceinline__ float bf2f(ushort_t u) {
    return __uint_as_float(((unsigned int)u) << 16);
}

// async global->LDS, 16B per lane, wave-uniform LDS base (HW: base + lane*16)
#define GLD16(gp, lp) __builtin_amdgcn_global_load_lds( \
    (const __attribute__((address_space(1))) void*)(gp), \
    (__attribute__((address_space(3))) void*)(lp), 16, 0, 0)

#define WAIT_VM0()   __builtin_amdgcn_s_waitcnt(0x0F70)  // vmcnt(0) only
#define WAIT_VM4()   __builtin_amdgcn_s_waitcnt(0x0F74)  // vmcnt(4) only
#define MEMFENCE()   asm volatile("" ::: "memory")

// ---------------------------------------------------------------------------
// fp32 -> bf16 converters
// ---------------------------------------------------------------------------
__global__ __launch_bounds__(256)
void cvt_kernel(const float* __restrict__ src, ushort_t* __restrict__ dst, int n)
{
    int i = (blockIdx.x * 256 + threadIdx.x) * 8;
    if (i >= n) return;
    float4 a = *(const float4*)(src + i);
    float4 b = *(const float4*)(src + i + 4);
    us8 r;
    r[0] = f2bf(a.x); r[1] = f2bf(a.y); r[2] = f2bf(a.z); r[3] = f2bf(a.w);
    r[4] = f2bf(b.x); r[5] = f2bf(b.y); r[6] = f2bf(b.z); r[7] = f2bf(b.w);
    *(us8*)(dst + i) = r;
}

__global__ __launch_bounds__(256)
void cvt_w4(const float* __restrict__ w0, const float* __restrict__ w1,
            const float* __restrict__ w2, const float* __restrict__ w3,
            ushort_t* __restrict__ dst)
{
    const int ten = blockIdx.y;
    const float* s = (ten == 0) ? w0 : (ten == 1) ? w1 : (ten == 2) ? w2 : w3;
    ushort_t* d = dst + (size_t)ten * (D_ * D_);
    int i = (blockIdx.x * 256 + threadIdx.x) * 8;
    float4 a = *(const float4*)(s + i);
    float4 b = *(const float4*)(s + i + 4);
    us8 r;
    r[0] = f2bf(a.x); r[1] = f2bf(a.y); r[2] = f2bf(a.z); r[3] = f2bf(a.w);
    r[4] = f2bf(b.x); r[5] = f2bf(b.y); r[6] = f2bf(b.z); r[7] = f2bf(b.w);
    *(us8*)(d + i) = r;
}

// ---------------------------------------------------------------------------
// MFMA GEMM: Y = A @ Bw^T + bias.  A:[M,K] bf16, Bw:[N,K] bf16 (torch weight).
// 128x128 tile, BK=32, 256 thr = 4 waves (2x2), 4x4 16x16x32 MFMAs per wave.
// DOUBLE-BUFFERED staging: prefetch next slab into alt LDS buffer, raw
// s_barrier + manual vmcnt(4) so prefetch stays in flight across barrier.
// mode 0: N=3072 fused QKV -> scatter Q(bf16,*0.125)/K(bf16)/V^T(bf16)
// mode 1: N=1024 -> bf16 Yb[m*1024+n]
// ---------------------------------------------------------------------------
__global__ __launch_bounds__(256)
void gemm_mfma(const ushort_t* __restrict__ A, const ushort_t* __restrict__ Bw,
               const float* __restrict__ bias0, const float* __restrict__ bias1,
               const float* __restrict__ bias2,
               ushort_t* __restrict__ Yb, ushort_t* __restrict__ Qo,
               ushort_t* __restrict__ Ko, ushort_t* __restrict__ Vo,
               int K, int mode)
{
    __shared__ __align__(16) ushort_t As[2][128 * 32];
    __shared__ __align__(16) ushort_t Bs[2][128 * 32];
    const int t = threadIdx.x;
    const int lane = t & 63, wave = t >> 6;
    const int wm = wave >> 1, wn = wave & 1;
    const int m0 = blockIdx.x * 128, n0 = blockIdx.y * 128;
    const int quad = lane >> 4, l15 = lane & 15;

    const int ch0 = wave * 2, ch1 = wave * 2 + 1;
    const int srow = lane >> 2;          // 0..15
    const int scol = (lane & 3) * 8;     // 0,8,16,24
    const ushort_t* Ap0 = A  + (size_t)(m0 + ch0 * 16 + srow) * K + scol;
    const ushort_t* Ap1 = A  + (size_t)(m0 + ch1 * 16 + srow) * K + scol;
    const ushort_t* Bp0 = Bw + (size_t)(n0 + ch0 * 16 + srow) * K + scol;
    const ushort_t* Bp1 = Bw + (size_t)(n0 + ch1 * 16 + srow) * K + scol;

    f32x4 acc[4][4] = {};

    // prefetch slab 0 into buffer 0
    GLD16(Ap0, As[0] + ch0 * 512);
    GLD16(Ap1, As[0] + ch1 * 512);
    GLD16(Bp0, Bs[0] + ch0 * 512);
    GLD16(Bp1, Bs[0] + ch1 * 512);

    const int nk = K >> 5;
    for (int ki = 0; ki < nk; ki++) {
        const int buf = ki & 1;
        if (ki + 1 < nk) {
            const int k1 = (ki + 1) << 5;
            GLD16(Ap0 + k1, As[buf ^ 1] + ch0 * 512);
            GLD16(Ap1 + k1, As[buf ^ 1] + ch1 * 512);
            GLD16(Bp0 + k1, Bs[buf ^ 1] + ch0 * 512);
            GLD16(Bp1 + k1, Bs[buf ^ 1] + ch1 * 512);
            WAIT_VM4();      // own slab-ki chunks landed; barrier certifies all
        } else {
            WAIT_VM0();
        }
        MEMFENCE();
        __builtin_amdgcn_s_barrier();
        MEMFENCE();

        bf16x8 af[4], bfr[4];
        #pragma unroll
        for (int i = 0; i < 4; i++)
            af[i] = *(const bf16x8*)(As[buf] + (64 * wm + 16 * i + l15) * 32 + quad * 8);
        #pragma unroll
        for (int j = 0; j < 4; j++)
            bfr[j] = *(const bf16x8*)(Bs[buf] + (64 * wn + 16 * j + l15) * 32 + quad * 8);
        #pragma unroll
        for (int i = 0; i < 4; i++)
            #pragma unroll
            for (int j = 0; j < 4; j++)
                acc[i][j] = __builtin_amdgcn_mfma_f32_16x16x32_bf16(af[i], bfr[j], acc[i][j], 0, 0, 0);

        MEMFENCE();
        __builtin_amdgcn_s_barrier();    // all reads of buf done before overwrite
        MEMFENCE();
    }

    // epilogue — C/D layout: row = quad*4+r, col = l15
    #pragma unroll
    for (int j = 0; j < 4; j++) {
        const int n = n0 + 64 * wn + 16 * j + l15;
        if (mode == 1) {
            const float bv = bias0[n];
            #pragma unroll
            for (int i = 0; i < 4; i++) {
                const int mrow = m0 + 64 * wm + 16 * i + quad * 4;
                ushort_t* yp = Yb + (size_t)mrow * D_ + n;
                #pragma unroll
                for (int r = 0; r < 4; r++)
                    yp[(size_t)r * D_] = f2bf(acc[i][j][r] + bv);
            }
        } else {
            const int sel = n >> 10, nn = n & 1023;
            const int hh = nn >> 6, dd = nn & 63;
            const float bv = (sel == 0 ? bias0 : (sel == 1 ? bias1 : bias2))[nn];
            const float scl = (sel == 0) ? 0.125f : 1.0f;
            #pragma unroll
            for (int i = 0; i < 4; i++) {
                const int mrow = m0 + 64 * wm + 16 * i + quad * 4;
                const int b = mrow >> 11;
                const int ss = mrow & (S_ - 1);
                #pragma unroll
                for (int r = 0; r < 4; r++) {
                    const float v = (acc[i][j][r] + bv) * scl;
                    const ushort_t bvv = f2bf(v);
                    if (sel == 0)
                        Qo[(((size_t)b * H_ + hh) * S_ + ss + r) * DH_ + dd] = bvv;
                    else if (sel == 1)
                        Ko[(((size_t)b * H_ + hh) * S_ + ss + r) * DH_ + dd] = bvv;
                    else
                        Vo[(((size_t)b * H_ + hh) * DH_ + dd) * S_ + ss + r] = bvv;
                }
            }
        }
    }
}

// ---------------------------------------------------------------------------
// MFMA flash attention (causal), transposed-score formulation.
//   S^T = K·Q^T  (C/D: row=key=quad*4+r, col=query=l15);  O^T = V^T·P^T.
// Equal-work pairing: block bx in [0,8) runs q-tiles {15-bx, bx}.
// Output written as bf16 [B,S,D].
// ---------------------------------------------------------------------------
__global__ __launch_bounds__(256, 2)
void attn_mfma(const ushort_t* __restrict__ Qb, const ushort_t* __restrict__ Kb,
               const ushort_t* __restrict__ Vt, ushort_t* __restrict__ outb)
{
    __shared__ __align__(16) ushort_t Ks[2][64 * 64];
    __shared__ __align__(16) ushort_t Vs[2][64 * 64];
    __shared__ __align__(16) ushort_t Ps[8][16 * 72];   // [wave*2+g][16q][64k+pad]
    const int t = threadIdx.x, lane = t & 63, w = t >> 6;
    const int bx = blockIdx.x;             // 0..7
    const int bh = blockIdx.y;
    const int quad = lane >> 4, l15 = lane & 15;
    const int rw = 32 * w;                 // wave's first query within q-tile

    const int c0 = 2 * w, c1 = 2 * w + 1;
    const int srow = lane >> 3;                   // 0..7 row within chunk
    const int scol = 8 * ((lane & 7) ^ srow);     // XOR-8 swizzled col (ushort)
    const ushort_t* KgB = Kb + (size_t)bh * S_ * DH_;
    const ushort_t* VgB = Vt + (size_t)bh * DH_ * S_;
    const ushort_t* Kg0 = KgB + (size_t)(c0 * 8 + srow) * DH_ + scol;
    const ushort_t* Kg1 = KgB + (size_t)(c1 * 8 + srow) * DH_ + scol;
    const ushort_t* Vg0 = VgB + (size_t)(c0 * 8 + srow) * S_ + scol;
    const ushort_t* Vg1 = VgB + (size_t)(c1 * 8 + srow) * S_ + scol;
    ushort_t* pw0 = Ps[w * 2 + 0];
    ushort_t* pw1 = Ps[w * 2 + 1];
    const int b = bh >> 4, hh = bh & (H_ - 1);

    for (int ph = 0; ph < 2; ph++) {
        const int qt = ph ? bx : (15 - bx);
        const int q0 = qt * 128;

        const ushort_t* qp = Qb + ((size_t)bh * S_ + q0 + rw + l15) * DH_ + quad * 8;
        const bf16x8 qf00 = *(const bf16x8*)(qp);
        const bf16x8 qf01 = *(const bf16x8*)(qp + 32);
        const bf16x8 qf10 = *(const bf16x8*)(qp + 16 * DH_);
        const bf16x8 qf11 = *(const bf16x8*)(qp + 16 * DH_ + 32);

        f32x4 o0[4] = {}, o1[4] = {};
        float m0v = -INFINITY, m1v = -INFINITY, l0v = 0.f, l1v = 0.f;

        WAIT_VM0();      // Q frags resident; vmcnt bookkeeping exact from here
        MEMFENCE();
        GLD16(Kg0, &Ks[0][c0 * 512]);
        GLD16(Kg1, &Ks[0][c1 * 512]);
        GLD16(Vg0, &Vs[0][c0 * 512]);
        GLD16(Vg1, &Vs[0][c1 * 512]);

        const int qg00 = q0 + rw;          // g=0 first query
        const int qg10 = q0 + rw + 16;     // g=1 first query
        const int last = 2 * qt + 1;

        for (int kt = 0; kt <= last; kt++) {
            const int buf = kt & 1;
            const int k0 = kt * 64;
            if (kt < last) {
                const size_t ko = (size_t)(k0 + 64) * DH_;
                GLD16(Kg0 + ko, &Ks[buf ^ 1][c0 * 512]);
                GLD16(Kg1 + ko, &Ks[buf ^ 1][c1 * 512]);
                GLD16(Vg0 + k0 + 64, &Vs[buf ^ 1][c0 * 512]);
                GLD16(Vg1 + k0 + 64, &Vs[buf ^ 1][c1 * 512]);
                WAIT_VM4();
            } else {
                WAIT_VM0();
            }
            MEMFENCE();
            __builtin_amdgcn_s_barrier();
            MEMFENCE();

            if (k0 <= qg10 + 15) {         // wave has at least one unmasked query
                const bool a0 = (k0 <= qg00 + 15);
                const ushort_t* kb = Ks[buf];
                const ushort_t* vb = Vs[buf];
                const int xr = l15 & 7;    // swizzle term (row&7) for frag reads

                bf16x8 kf[4][2];
                #pragma unroll
                for (int ct = 0; ct < 4; ct++)
                    #pragma unroll
                    for (int h = 0; h < 2; h++)
                        kf[ct][h] = *(const bf16x8*)(kb + (ct * 16 + l15) * 64 +
                                                     8 * ((h * 4 + quad) ^ xr));

                f32x4 sc0[4] = {}, sc1[4] = {};
                #pragma unroll
                for (int ct = 0; ct < 4; ct++) {
                    sc1[ct] = __builtin_amdgcn_mfma_f32_16x16x32_bf16(kf[ct][0], qf10, sc1[ct], 0, 0, 0);
                    sc1[ct] = __builtin_amdgcn_mfma_f32_16x16x32_bf16(kf[ct][1], qf11, sc1[ct], 0, 0, 0);
                }
                if (a0) {
                    #pragma unroll
                    for (int ct = 0; ct < 4; ct++) {
                        sc0[ct] = __builtin_amdgcn_mfma_f32_16x16x32_bf16(kf[ct][0], qf00, sc0[ct], 0, 0, 0);
                        sc0[ct] = __builtin_amdgcn_mfma_f32_16x16x32_bf16(kf[ct][1], qf01, sc0[ct], 0, 0, 0);
                    }
                }

                bf16x8 vf[4][2];
                #pragma unroll
                for (int mt = 0; mt < 4; mt++)
                    #pragma unroll
                    for (int h = 0; h < 2; h++)
                        vf[mt][h] = *(const bf16x8*)(vb + (mt * 16 + l15) * 64 +
                                                     8 * ((h * 4 + quad) ^ xr));

                if (k0 + 63 > qg10) {
                    const int qq = qg10 + l15;
                    #pragma unroll
                    for (int ct = 0; ct < 4; ct++) {
                        const int key = k0 + ct * 16 + quad * 4;
                        #pragma unroll
                        for (int r = 0; r < 4; r++)
                            if (key + r > qq) sc1[ct][r] = -INFINITY;
                    }
                }
                if (a0 && k0 + 63 > qg00) {
                    const int qq = qg00 + l15;
                    #pragma unroll
                    for (int ct = 0; ct < 4; ct++) {
                        const int key = k0 + ct * 16 + quad * 4;
                        #pragma unroll
                        for (int r = 0; r < 4; r++)
                            if (key + r > qq) sc0[ct][r] = -INFINITY;
                    }
                }

                float mx0 = -INFINITY, mx1 = sc1[0][0];
                #pragma unroll
                for (int ct = 0; ct < 4; ct++)
                    #pragma unroll
                    for (int r = 0; r < 4; r++) mx1 = fmaxf(mx1, sc1[ct][r]);
                if (a0) {
                    mx0 = sc0[0][0];
                    #pragma unroll
                    for (int ct = 0; ct < 4; ct++)
                        #pragma unroll
                        for (int r = 0; r < 4; r++) mx0 = fmaxf(mx0, sc0[ct][r]);
                }
                mx1 = fmaxf(mx1, __shfl_xor(mx1, 16));
                mx0 = fmaxf(mx0, __shfl_xor(mx0, 16));
                mx1 = fmaxf(mx1, __shfl_xor(mx1, 32));
                mx0 = fmaxf(mx0, __shfl_xor(mx0, 32));

                const float mn1 = fmaxf(m1v, mx1);
                const float al1 = __expf(m1v - mn1);
                m1v = mn1;
                const float mn0 = a0 ? fmaxf(m0v, mx0) : m0v;
                const float al0 = a0 ? __expf(m0v - mn0) : 1.f;
                m0v = mn0;

                float rs0 = 0.f, rs1 = 0.f;
                #pragma unroll
                for (int ct = 0; ct < 4; ct++) {
                    us4 pk;
                    #pragma unroll
                    for (int r = 0; r < 4; r++) {
                        const float p = __expf(sc1[ct][r] - mn1);
                        rs1 += p;
                        pk[r] = f2bf(p);
                    }
                    *(us4*)(pw1 + l15 * 72 + ct * 16 + quad * 4) = pk;
                }
                if (a0) {
                    #pragma unroll
                    for (int ct = 0; ct < 4; ct++) {
                        us4 pk;
                        #pragma unroll
                        for (int r = 0; r < 4; r++) {
                            const float p = __expf(sc0[ct][r] - mn0);
                            rs0 += p;
                            pk[r] = f2bf(p);
                        }
                        *(us4*)(pw0 + l15 * 72 + ct * 16 + quad * 4) = pk;
                    }
                }
                rs1 += __shfl_xor(rs1, 16);
                rs0 += __shfl_xor(rs0, 16);
                rs1 += __shfl_xor(rs1, 32);
                rs0 += __shfl_xor(rs0, 32);
                l1v = l1v * al1 + rs1;
                if (a0) l0v = l0v * al0 + rs0;

                #pragma unroll
                for (int mt = 0; mt < 4; mt++)
                    #pragma unroll
                    for (int r = 0; r < 4; r++) { o1[mt][r] *= al1; o0[mt][r] *= al0; }

                const bf16x8 pf10 = *(const bf16x8*)(pw1 + l15 * 72 + quad * 8);
                const bf16x8 pf11 = *(const bf16x8*)(pw1 + l15 * 72 + 32 + quad * 8);
                #pragma unroll
                for (int mt = 0; mt < 4; mt++) {
                    o1[mt] = __builtin_amdgcn_mfma_f32_16x16x32_bf16(vf[mt][0], pf10, o1[mt], 0, 0, 0);
                    o1[mt] = __builtin_amdgcn_mfma_f32_16x16x32_bf16(vf[mt][1], pf11, o1[mt], 0, 0, 0);
                }
                if (a0) {
                    const bf16x8 pf00 = *(const bf16x8*)(pw0 + l15 * 72 + quad * 8);
                    const bf16x8 pf01 = *(const bf16x8*)(pw0 + l15 * 72 + 32 + quad * 8);
                    #pragma unroll
                    for (int mt = 0; mt < 4; mt++) {
                        o0[mt] = __builtin_amdgcn_mfma_f32_16x16x32_bf16(vf[mt][0], pf00, o0[mt], 0, 0, 0);
                        o0[mt] = __builtin_amdgcn_mfma_f32_16x16x32_bf16(vf[mt][1], pf01, o0[mt], 0, 0, 0);
                    }
                }
            }
            MEMFENCE();
            __builtin_amdgcn_s_barrier();    // all reads of buf done before overwrite
            MEMFENCE();
        }

        // epilogue: O^T lane layout dh=mt*16+quad*4+r, query=l15 ; bf16 stores
        {
            const float inv0 = 1.0f / l0v, inv1 = 1.0f / l1v;
            const int query0 = q0 + rw + l15;
            ushort_t* ob0 = outb + ((size_t)(b * S_ + query0)) * D_ + hh * DH_ + quad * 4;
            ushort_t* ob1 = ob0 + (size_t)16 * D_;
            #pragma unroll
            for (int mt = 0; mt < 4; mt++) {
                us4 r0, r1;
                #pragma unroll
                for (int r = 0; r < 4; r++) {
                    r0[r] = f2bf(o0[mt][r] * inv0);
                    r1[r] = f2bf(o1[mt][r] * inv1);
                }
                *(us4*)(ob0 + mt * 16) = r0;
                *(us4*)(ob1 + mt * 16) = r1;
            }
        }
    }
}

// ---------------------------------------------------------------------------
// LN1: out_bf = LayerNorm(X_f32 + R_bf16) * g + b   (bf16 output only)
// ---------------------------------------------------------------------------
__global__ __launch_bounds__(256)
void ln_f32bf(const float* __restrict__ X, const ushort_t* __restrict__ R,
              const float* __restrict__ g, const float* __restrict__ bia,
              ushort_t* __restrict__ out_bf)
{
    const int row = blockIdx.x;
    const int t   = threadIdx.x;
    const float4 xv = ((const float4*)(X + (size_t)row * D_))[t];
    const us4 rv = *(const us4*)(R + (size_t)row * D_ + t * 4);
    float s0 = xv.x + bf2f(rv[0]);
    float s1 = xv.y + bf2f(rv[1]);
    float s2 = xv.z + bf2f(rv[2]);
    float s3 = xv.w + bf2f(rv[3]);

    float sum = s0 + s1 + s2 + s3;
    float sq  = s0*s0 + s1*s1 + s2*s2 + s3*s3;
    #pragma unroll
    for (int off = 32; off > 0; off >>= 1) {
        sum += __shfl_down(sum, off);
        sq  += __shfl_down(sq,  off);
    }
    __shared__ float wsum[4], wsq[4], stat[2];
    const int wid = t >> 6, lane = t & 63;
    if (lane == 0) { wsum[wid] = sum; wsq[wid] = sq; }
    __syncthreads();
    if (t == 0) {
        float S = wsum[0] + wsum[1] + wsum[2] + wsum[3];
        float Q = wsq[0]  + wsq[1]  + wsq[2]  + wsq[3];
        float mean = S * (1.0f / D_);
        float var  = Q * (1.0f / D_) - mean * mean;
        stat[0] = mean;
        stat[1] = rsqrtf(var + 1e-5f);
    }
    __syncthreads();
    const float mean = stat[0], inv = stat[1];
    const float4 gv = ((const float4*)g)[t];
    const float4 bv = ((const float4*)bia)[t];
    us4 ob;
    ob[0] = f2bf((s0 - mean) * inv * gv.x + bv.x);
    ob[1] = f2bf((s1 - mean) * inv * gv.y + bv.y);
    ob[2] = f2bf((s2 - mean) * inv * gv.z + bv.z);
    ob[3] = f2bf((s3 - mean) * inv * gv.w + bv.w);
    *(us4*)(out_bf + (size_t)row * D_ + t * 4) = ob;
}

// ---------------------------------------------------------------------------
// LN2: out_f32 = LayerNorm(Hb_bf16 + Yb_bf16) * g + b
// ---------------------------------------------------------------------------
__global__ __launch_bounds__(256)
void ln_bfbf(const ushort_t* __restrict__ Hb, const ushort_t* __restrict__ Yb,
             const float* __restrict__ g, const float* __restrict__ bia,
             float* __restrict__ outf)
{
    const int row = blockIdx.x;
    const int t   = threadIdx.x;
    const us4 hv = *(const us4*)(Hb + (size_t)row * D_ + t * 4);
    const us4 yv = *(const us4*)(Yb + (size_t)row * D_ + t * 4);
    float s0 = bf2f(hv[0]) + bf2f(yv[0]);
    float s1 = bf2f(hv[1]) + bf2f(yv[1]);
    float s2 = bf2f(hv[2]) + bf2f(yv[2]);
    float s3 = bf2f(hv[3]) + bf2f(yv[3]);

    float sum = s0 + s1 + s2 + s3;
    float sq  = s0*s0 + s1*s1 + s2*s2 + s3*s3;
    #pragma unroll
    for (int off = 32; off > 0; off >>= 1) {
        sum += __shfl_down(sum, off);
        sq  += __shfl_down(sq,  off);
    }
    __shared__ float wsum[4], wsq[4], stat[2];
    const int wid = t >> 6, lane = t & 63;
    if (lane == 0) { wsum[wid] = sum; wsq[wid] = sq; }
    __syncthreads();
    if (t == 0) {
        float S = wsum[0] + wsum[1] + wsum[2] + wsum[3];
        float Q = wsq[0]  + wsq[1]  + wsq[2]  + wsq[3];
        float mean = S * (1.0f / D_);
        float var  = Q * (1.0f / D_) - mean * mean;
        stat[0] = mean;
        stat[1] = rsqrtf(var + 1e-5f);
    }
    __syncthreads();
    const float mean = stat[0], inv = stat[1];
    const float4 gv = ((const float4*)g)[t];
    const float4 bv = ((const float4*)bia)[t];
    float4 o;
    o.x = (s0 - mean) * inv * gv.x + bv.x;
    o.y = (s1 - mean) * inv * gv.y + bv.y;
    o.z = (s2 - mean) * inv * gv.z + bv.z;
    o.w = (s3 - mean) * inv * gv.w + bv.w;
    ((float4*)(outf + (size_t)row * D_))[t] = o;
}

// ---------------------------------------------------------------------------
extern "C" void kernel_launch(void* const* d_in, const int* in_sizes, int n_in,
                              void* d_out, int out_size, void* d_ws, size_t ws_size,
                              hipStream_t stream)
{
    const float* x      = (const float*)d_in[0];
    const float* wq_w   = (const float*)d_in[1];
    const float* wq_b   = (const float*)d_in[2];
    const float* wk_w   = (const float*)d_in[3];
    const float* wk_b   = (const float*)d_in[4];
    const float* wv_w   = (const float*)d_in[5];
    const float* wv_b   = (const float*)d_in[6];
    const float* ln1_g  = (const float*)d_in[7];
    const float* ln1_b  = (const float*)d_in[8];
    const float* lin1_w = (const float*)d_in[9];
    const float* lin1_b = (const float*)d_in[10];
    const float* ln2_g  = (const float*)d_in[11];
    const float* ln2_b  = (const float*)d_in[12];
    float* out = (float*)d_out;

    char* base = (char*)d_ws;
    // ws layout (aliased through the pipeline):
    //   [0        ,16M): x_bf   -> attn_bf (x_bf dead after QKV GEMM)
    //   [16M      ,24M): w_bf (wq|wk|wv|lin1)
    //   [24M+1M   ,40M+1M): Qbf  -> h_bf   (Qbf dead after attention)
    //   [40M+2M   ,56M+2M): Kbf  -> y_bf   (Kbf dead after attention)
    //   [56M+3M   ,72M+3M): Vtp
    ushort_t* x_bf    = (ushort_t*)(base);
    ushort_t* attn_bf = (ushort_t*)(base);
    ushort_t* w_bf    = (ushort_t*)(base + 16777216);
    ushort_t* Qbf     = (ushort_t*)(base + 25165824);
    ushort_t* h_bf    = (ushort_t*)(base + 25165824);
    ushort_t* Kbf     = (ushort_t*)(base + 41943040);
    ushort_t* y_bf    = (ushort_t*)(base + 41943040);
    ushort_t* Vtp     = (ushort_t*)(base + 58720256);

    cvt_kernel<<<dim3((M_ * D_) / 2048), 256, 0, stream>>>(x, x_bf, M_ * D_);
    cvt_w4<<<dim3((D_ * D_) / 2048, 4), 256, 0, stream>>>(wq_w, wk_w, wv_w, lin1_w, w_bf);

    gemm_mfma<<<dim3(M_ / 128, 3072 / 128), 256, 0, stream>>>(
        x_bf, w_bf, wq_b, wk_b, wv_b, nullptr, Qbf, Kbf, Vtp, D_, 0);

    attn_mfma<<<dim3(8, B_ * H_), 256, 0, stream>>>(Qbf, Kbf, Vtp, attn_bf);

    ln_f32bf<<<M_, 256, 0, stream>>>(x, attn_bf, ln1_g, ln1_b, h_bf);

    gemm_mfma<<<dim3(M_ / 128, D_ / 128), 256, 0, stream>>>(
        h_bf, w_bf + 3 * D_ * D_, lin1_b, nullptr, nullptr, y_bf, nullptr, nullptr, nullptr, D_, 1);

    ln_bfbf<<<M_, 256, 0, stream>>>(h_bf, y_bf, ln2_g, ln2_b, out);
}

// Round 8
// 306.824 us; speedup vs baseline: 1.5554x; 1.0619x over previous
//
#include <hip/hip_runtime.h>
#include <math.h>

#define B_  4
#define S_  2048
#define D_  1024
#define H_  16
#define DH_ 64
#define M_  (B_*S_)

typedef unsigned short ushort_t;
typedef __attribute__((ext_vector_type(8))) __bf16 bf16x8;
typedef __attribute__((ext_vector_type(4))) float f32x4;
typedef __attribute__((ext_vector_type(8))) unsigned short us8;
typedef __attribute__((ext_vector_type(4))) unsigned short us4;

__device__ __forceinline__ ushort_t f2bf(float f) {
    unsigned int u = __float_as_uint(f);
    u = (u + 0x7fffu + ((u >> 16) & 1u)) >> 16;   // RNE
    return (ushort_t)u;
}
__device__ __forceinline__ float bf2f(ushort_t u) {
    return __uint_as_float(((unsigned int)u) << 16);
}

// async global->LDS, 16B per lane, wave-uniform LDS base (HW: base + lane*16)
#define GLD16(gp, lp) __builtin_amdgcn_global_load_lds( \
    (const __attribute__((address_space(1))) void*)(gp), \
    (__attribute__((address_space(3))) void*)(lp), 16, 0, 0)

#define WAIT_VM0()   __builtin_amdgcn_s_waitcnt(0x0F70)  // vmcnt(0) only
#define WAIT_VM4()   __builtin_amdgcn_s_waitcnt(0x0F74)  // vmcnt(4) only
#define WAIT_VM8()   __builtin_amdgcn_s_waitcnt(0x0F78)  // vmcnt(8) only
#define MEMFENCE()   asm volatile("" ::: "memory")

// ---------------------------------------------------------------------------
// merged fp32 -> bf16 converter: blocks 0..4095 convert x (8.4M elems),
// blocks 4096+k*512.. convert weight k (1M elems each), k = 0..3.
// ---------------------------------------------------------------------------
__global__ __launch_bounds__(256)
void cvt_all(const float* __restrict__ x,
             const float* __restrict__ w0, const float* __restrict__ w1,
             const float* __restrict__ w2, const float* __restrict__ w3,
             ushort_t* __restrict__ xd, ushort_t* __restrict__ wd)
{
    const int bid = blockIdx.x;
    const float* s;
    ushort_t* d;
    int i;
    if (bid < 4096) {
        s = x; d = xd; i = bid * 2048 + threadIdx.x * 8;
    } else {
        const int k = (bid - 4096) >> 9;
        const int r = (bid - 4096) & 511;
        s = (k == 0) ? w0 : (k == 1) ? w1 : (k == 2) ? w2 : w3;
        d = wd + (size_t)k * (D_ * D_);
        i = r * 2048 + threadIdx.x * 8;
    }
    float4 a = *(const float4*)(s + i);
    float4 b = *(const float4*)(s + i + 4);
    us8 r8;
    r8[0] = f2bf(a.x); r8[1] = f2bf(a.y); r8[2] = f2bf(a.z); r8[3] = f2bf(a.w);
    r8[4] = f2bf(b.x); r8[5] = f2bf(b.y); r8[6] = f2bf(b.z); r8[7] = f2bf(b.w);
    *(us8*)(d + i) = r8;
}

// ---------------------------------------------------------------------------
// MFMA GEMM: Y = A @ Bw^T + bias.  A:[M,K] bf16, Bw:[N,K] bf16 (torch weight).
// 128x128 tile, BK=32, 256 thr = 4 waves (2x2), 4x4 16x16x32 MFMAs per wave.
// TRIPLE-BUFFERED staging, prefetch depth 2 (raw s_barrier + vmcnt(8)) to
// cover ~2 loop bodies (~500cyc) of load latency.
// mode 0: N=3072 fused QKV -> scatter Q(bf16, *0.125*log2e)/K(bf16)/V^T(bf16)
// mode 1: N=1024 -> bf16 Yb[m*1024+n]
// ---------------------------------------------------------------------------
__global__ __launch_bounds__(256)
void gemm_mfma(const ushort_t* __restrict__ A, const ushort_t* __restrict__ Bw,
               const float* __restrict__ bias0, const float* __restrict__ bias1,
               const float* __restrict__ bias2,
               ushort_t* __restrict__ Yb, ushort_t* __restrict__ Qo,
               ushort_t* __restrict__ Ko, ushort_t* __restrict__ Vo,
               int K, int mode)
{
    __shared__ __align__(16) ushort_t As[3][128 * 32];
    __shared__ __align__(16) ushort_t Bs[3][128 * 32];
    const int t = threadIdx.x;
    const int lane = t & 63, wave = t >> 6;
    const int wm = wave >> 1, wn = wave & 1;
    const int m0 = blockIdx.x * 128, n0 = blockIdx.y * 128;
    const int quad = lane >> 4, l15 = lane & 15;

    const int ch0 = wave * 2, ch1 = wave * 2 + 1;
    const int srow = lane >> 2;          // 0..15
    const int scol = (lane & 3) * 8;     // 0,8,16,24
    const ushort_t* Ap0 = A  + (size_t)(m0 + ch0 * 16 + srow) * K + scol;
    const ushort_t* Ap1 = A  + (size_t)(m0 + ch1 * 16 + srow) * K + scol;
    const ushort_t* Bp0 = Bw + (size_t)(n0 + ch0 * 16 + srow) * K + scol;
    const ushort_t* Bp1 = Bw + (size_t)(n0 + ch1 * 16 + srow) * K + scol;

    f32x4 acc[4][4] = {};

    // prefetch slabs 0,1 into buffers 0,1
    GLD16(Ap0, As[0] + ch0 * 512);
    GLD16(Ap1, As[0] + ch1 * 512);
    GLD16(Bp0, Bs[0] + ch0 * 512);
    GLD16(Bp1, Bs[0] + ch1 * 512);
    GLD16(Ap0 + 32, As[1] + ch0 * 512);
    GLD16(Ap1 + 32, As[1] + ch1 * 512);
    GLD16(Bp0 + 32, Bs[1] + ch0 * 512);
    GLD16(Bp1 + 32, Bs[1] + ch1 * 512);

    const int nk = K >> 5;
    for (int ki = 0; ki < nk; ki++) {
        const int buf = ki % 3;
        if (ki + 2 < nk) {
            const int k2 = (ki + 2) << 5;
            const int b2 = (ki + 2) % 3;
            GLD16(Ap0 + k2, As[b2] + ch0 * 512);
            GLD16(Ap1 + k2, As[b2] + ch1 * 512);
            GLD16(Bp0 + k2, Bs[b2] + ch0 * 512);
            GLD16(Bp1 + k2, Bs[b2] + ch1 * 512);
            WAIT_VM8();     // own slab-ki loads landed; 8 (2 slabs) in flight
        } else if (ki + 1 < nk) {
            WAIT_VM4();
        } else {
            WAIT_VM0();
        }
        MEMFENCE();
        __builtin_amdgcn_s_barrier();
        MEMFENCE();

        bf16x8 af[4], bfr[4];
        #pragma unroll
        for (int i = 0; i < 4; i++)
            af[i] = *(const bf16x8*)(As[buf] + (64 * wm + 16 * i + l15) * 32 + quad * 8);
        #pragma unroll
        for (int j = 0; j < 4; j++)
            bfr[j] = *(const bf16x8*)(Bs[buf] + (64 * wn + 16 * j + l15) * 32 + quad * 8);
        #pragma unroll
        for (int i = 0; i < 4; i++)
            #pragma unroll
            for (int j = 0; j < 4; j++)
                acc[i][j] = __builtin_amdgcn_mfma_f32_16x16x32_bf16(af[i], bfr[j], acc[i][j], 0, 0, 0);

        MEMFENCE();
        __builtin_amdgcn_s_barrier();    // all reads of buf done before overwrite
        MEMFENCE();
    }

    // epilogue — C/D layout: row = quad*4+r, col = l15
    #pragma unroll
    for (int j = 0; j < 4; j++) {
        const int n = n0 + 64 * wn + 16 * j + l15;
        if (mode == 1) {
            const float bv = bias0[n];
            #pragma unroll
            for (int i = 0; i < 4; i++) {
                const int mrow = m0 + 64 * wm + 16 * i + quad * 4;
                ushort_t* yp = Yb + (size_t)mrow * D_ + n;
                #pragma unroll
                for (int r = 0; r < 4; r++)
                    yp[(size_t)r * D_] = f2bf(acc[i][j][r] + bv);
            }
        } else {
            const int sel = n >> 10, nn = n & 1023;
            const int hh = nn >> 6, dd = nn & 63;
            const float bv = (sel == 0 ? bias0 : (sel == 1 ? bias1 : bias2))[nn];
            // Q pre-scaled by 0.125*log2(e) so attention exp is exp2-native
            const float scl = (sel == 0) ? 0.18033688f : 1.0f;
            #pragma unroll
            for (int i = 0; i < 4; i++) {
                const int mrow = m0 + 64 * wm + 16 * i + quad * 4;
                const int b = mrow >> 11;
                const int ss = mrow & (S_ - 1);
                if (sel == 2) {
                    // V^T [B,H,dh,S]: r is contiguous -> one us4 store
                    us4 pk;
                    #pragma unroll
                    for (int r = 0; r < 4; r++)
                        pk[r] = f2bf(acc[i][j][r] + bv);
                    *(us4*)(Vo + (((size_t)b * H_ + hh) * DH_ + dd) * S_ + ss) = pk;
                } else {
                    ushort_t* dst = (sel == 0) ? Qo : Ko;
                    #pragma unroll
                    for (int r = 0; r < 4; r++) {
                        const float v = (acc[i][j][r] + bv) * scl;
                        dst[(((size_t)b * H_ + hh) * S_ + ss + r) * DH_ + dd] = f2bf(v);
                    }
                }
            }
        }
    }
}

// ---------------------------------------------------------------------------
// MFMA flash attention (causal), transposed-score, STATIC-MAX softmax.
//   S^T = K·Q^T  (C/D: row=key=quad*4+r, col=query=l15);  O^T = V^T·P^T.
// Q pre-scaled by 0.125*log2e -> p = exp2(s' - 16) via accumulator init -16.
// No online max/rescale; l accumulates per-lane, reduced once in epilogue.
// Equal-work pairing: block bx in [0,8) runs q-tiles {15-bx, bx}.
// ---------------------------------------------------------------------------
__global__ __launch_bounds__(256, 2)
void attn_mfma(const ushort_t* __restrict__ Qb, const ushort_t* __restrict__ Kb,
               const ushort_t* __restrict__ Vt, ushort_t* __restrict__ outb)
{
    __shared__ __align__(16) ushort_t Ks[2][64 * 64];
    __shared__ __align__(16) ushort_t Vs[2][64 * 64];
    __shared__ __align__(16) ushort_t Ps[8][16 * 72];   // [wave*2+g][16q][64k+pad]
    const int t = threadIdx.x, lane = t & 63, w = t >> 6;
    const int bx = blockIdx.x;             // 0..7
    const int bh = blockIdx.y;
    const int quad = lane >> 4, l15 = lane & 15;
    const int rw = 32 * w;                 // wave's first query within q-tile

    const int c0 = 2 * w, c1 = 2 * w + 1;
    const int srow = lane >> 3;                   // 0..7 row within chunk
    const int scol = 8 * ((lane & 7) ^ srow);     // XOR-8 swizzled col (ushort)
    const ushort_t* KgB = Kb + (size_t)bh * S_ * DH_;
    const ushort_t* VgB = Vt + (size_t)bh * DH_ * S_;
    const ushort_t* Kg0 = KgB + (size_t)(c0 * 8 + srow) * DH_ + scol;
    const ushort_t* Kg1 = KgB + (size_t)(c1 * 8 + srow) * DH_ + scol;
    const ushort_t* Vg0 = VgB + (size_t)(c0 * 8 + srow) * S_ + scol;
    const ushort_t* Vg1 = VgB + (size_t)(c1 * 8 + srow) * S_ + scol;
    ushort_t* pw0 = Ps[w * 2 + 0];
    ushort_t* pw1 = Ps[w * 2 + 1];
    const int b = bh >> 4, hh = bh & (H_ - 1);

    for (int ph = 0; ph < 2; ph++) {
        const int qt = ph ? bx : (15 - bx);
        const int q0 = qt * 128;

        const ushort_t* qp = Qb + ((size_t)bh * S_ + q0 + rw + l15) * DH_ + quad * 8;
        const bf16x8 qf00 = *(const bf16x8*)(qp);
        const bf16x8 qf01 = *(const bf16x8*)(qp + 32);
        const bf16x8 qf10 = *(const bf16x8*)(qp + 16 * DH_);
        const bf16x8 qf11 = *(const bf16x8*)(qp + 16 * DH_ + 32);

        f32x4 o0[4] = {}, o1[4] = {};
        float la0 = 0.f, la1 = 0.f;        // per-lane partial row-sum of P

        WAIT_VM0();      // Q frags resident; vmcnt bookkeeping exact from here
        MEMFENCE();
        GLD16(Kg0, &Ks[0][c0 * 512]);
        GLD16(Kg1, &Ks[0][c1 * 512]);
        GLD16(Vg0, &Vs[0][c0 * 512]);
        GLD16(Vg1, &Vs[0][c1 * 512]);

        const int qg00 = q0 + rw;          // g=0 first query
        const int qg10 = q0 + rw + 16;     // g=1 first query
        const int last = 2 * qt + 1;

        for (int kt = 0; kt <= last; kt++) {
            const int buf = kt & 1;
            const int k0 = kt * 64;
            if (kt < last) {
                const size_t ko = (size_t)(k0 + 64) * DH_;
                GLD16(Kg0 + ko, &Ks[buf ^ 1][c0 * 512]);
                GLD16(Kg1 + ko, &Ks[buf ^ 1][c1 * 512]);
                GLD16(Vg0 + k0 + 64, &Vs[buf ^ 1][c0 * 512]);
                GLD16(Vg1 + k0 + 64, &Vs[buf ^ 1][c1 * 512]);
                WAIT_VM4();
            } else {
                WAIT_VM0();
            }
            MEMFENCE();
            __builtin_amdgcn_s_barrier();
            MEMFENCE();

            if (k0 <= qg10 + 15) {         // wave has at least one unmasked query
                const bool a0 = (k0 <= qg00 + 15);
                const ushort_t* kb = Ks[buf];
                const ushort_t* vb = Vs[buf];
                const int xr = l15 & 7;    // swizzle term (row&7) for frag reads

                bf16x8 kf[4][2];
                #pragma unroll
                for (int ct = 0; ct < 4; ct++)
                    #pragma unroll
                    for (int h = 0; h < 2; h++)
                        kf[ct][h] = *(const bf16x8*)(kb + (ct * 16 + l15) * 64 +
                                                     8 * ((h * 4 + quad) ^ xr));

                // scores with C preloaded to -16 (static softmax shift)
                const f32x4 cinit = { -16.f, -16.f, -16.f, -16.f };
                f32x4 sc0[4], sc1[4];
                #pragma unroll
                for (int ct = 0; ct < 4; ct++) { sc0[ct] = cinit; sc1[ct] = cinit; }
                #pragma unroll
                for (int ct = 0; ct < 4; ct++) {
                    sc1[ct] = __builtin_amdgcn_mfma_f32_16x16x32_bf16(kf[ct][0], qf10, sc1[ct], 0, 0, 0);
                    sc1[ct] = __builtin_amdgcn_mfma_f32_16x16x32_bf16(kf[ct][1], qf11, sc1[ct], 0, 0, 0);
                }
                if (a0) {
                    #pragma unroll
                    for (int ct = 0; ct < 4; ct++) {
                        sc0[ct] = __builtin_amdgcn_mfma_f32_16x16x32_bf16(kf[ct][0], qf00, sc0[ct], 0, 0, 0);
                        sc0[ct] = __builtin_amdgcn_mfma_f32_16x16x32_bf16(kf[ct][1], qf01, sc0[ct], 0, 0, 0);
                    }
                }

                bf16x8 vf[4][2];
                #pragma unroll
                for (int mt = 0; mt < 4; mt++)
                    #pragma unroll
                    for (int h = 0; h < 2; h++)
                        vf[mt][h] = *(const bf16x8*)(vb + (mt * 16 + l15) * 64 +
                                                     8 * ((h * 4 + quad) ^ xr));

                if (k0 + 63 > qg10) {      // causal mask: diagonal band only
                    const int qq = qg10 + l15;
                    #pragma unroll
                    for (int ct = 0; ct < 4; ct++) {
                        const int key = k0 + ct * 16 + quad * 4;
                        #pragma unroll
                        for (int r = 0; r < 4; r++)
                            if (key + r > qq) sc1[ct][r] = -1e30f;
                    }
                }
                if (a0 && k0 + 63 > qg00) {
                    const int qq = qg00 + l15;
                    #pragma unroll
                    for (int ct = 0; ct < 4; ct++) {
                        const int key = k0 + ct * 16 + quad * 4;
                        #pragma unroll
                        for (int r = 0; r < 4; r++)
                            if (key + r > qq) sc0[ct][r] = -1e30f;
                    }
                }

                // p = exp2(score - 16); accumulate per-lane l; truncation-pack
                #pragma unroll
                for (int ct = 0; ct < 4; ct++) {
                    us4 pk;
                    #pragma unroll
                    for (int r = 0; r < 4; r++) {
                        const float p = exp2f(sc1[ct][r]);
                        la1 += p;
                        pk[r] = (ushort_t)(__float_as_uint(p) >> 16);
                    }
                    *(us4*)(pw1 + l15 * 72 + ct * 16 + quad * 4) = pk;
                }
                if (a0) {
                    #pragma unroll
                    for (int ct = 0; ct < 4; ct++) {
                        us4 pk;
                        #pragma unroll
                        for (int r = 0; r < 4; r++) {
                            const float p = exp2f(sc0[ct][r]);
                            la0 += p;
                            pk[r] = (ushort_t)(__float_as_uint(p) >> 16);
                        }
                        *(us4*)(pw0 + l15 * 72 + ct * 16 + quad * 4) = pk;
                    }
                }

                // O^T += V^T · P^T  (B-frag: n=query=l15, k=key=h*32+quad*8+j)
                const bf16x8 pf10 = *(const bf16x8*)(pw1 + l15 * 72 + quad * 8);
                const bf16x8 pf11 = *(const bf16x8*)(pw1 + l15 * 72 + 32 + quad * 8);
                #pragma unroll
                for (int mt = 0; mt < 4; mt++) {
                    o1[mt] = __builtin_amdgcn_mfma_f32_16x16x32_bf16(vf[mt][0], pf10, o1[mt], 0, 0, 0);
                    o1[mt] = __builtin_amdgcn_mfma_f32_16x16x32_bf16(vf[mt][1], pf11, o1[mt], 0, 0, 0);
                }
                if (a0) {
                    const bf16x8 pf00 = *(const bf16x8*)(pw0 + l15 * 72 + quad * 8);
                    const bf16x8 pf01 = *(const bf16x8*)(pw0 + l15 * 72 + 32 + quad * 8);
                    #pragma unroll
                    for (int mt = 0; mt < 4; mt++) {
                        o0[mt] = __builtin_amdgcn_mfma_f32_16x16x32_bf16(vf[mt][0], pf00, o0[mt], 0, 0, 0);
                        o0[mt] = __builtin_amdgcn_mfma_f32_16x16x32_bf16(vf[mt][1], pf01, o0[mt], 0, 0, 0);
                    }
                }
            }
            MEMFENCE();
            __builtin_amdgcn_s_barrier();    // all reads of buf done before overwrite
            MEMFENCE();
        }

        // epilogue: reduce l across quads once; normalize; bf16 stores
        {
            la0 += __shfl_xor(la0, 16);
            la1 += __shfl_xor(la1, 16);
            la0 += __shfl_xor(la0, 32);
            la1 += __shfl_xor(la1, 32);
            const float inv0 = 1.0f / la0, inv1 = 1.0f / la1;
            const int query0 = q0 + rw + l15;
            ushort_t* ob0 = outb + ((size_t)(b * S_ + query0)) * D_ + hh * DH_ + quad * 4;
            ushort_t* ob1 = ob0 + (size_t)16 * D_;
            #pragma unroll
            for (int mt = 0; mt < 4; mt++) {
                us4 r0, r1;
                #pragma unroll
                for (int r = 0; r < 4; r++) {
                    r0[r] = f2bf(o0[mt][r] * inv0);
                    r1[r] = f2bf(o1[mt][r] * inv1);
                }
                *(us4*)(ob0 + mt * 16) = r0;
                *(us4*)(ob1 + mt * 16) = r1;
            }
        }
    }
}

// ---------------------------------------------------------------------------
// LN1: out_bf = LayerNorm(X_f32 + R_bf16) * g + b   (bf16 output only)
// ---------------------------------------------------------------------------
__global__ __launch_bounds__(256)
void ln_f32bf(const float* __restrict__ X, const ushort_t* __restrict__ R,
              const float* __restrict__ g, const float* __restrict__ bia,
              ushort_t* __restrict__ out_bf)
{
    const int row = blockIdx.x;
    const int t   = threadIdx.x;
    const float4 xv = ((const float4*)(X + (size_t)row * D_))[t];
    const us4 rv = *(const us4*)(R + (size_t)row * D_ + t * 4);
    float s0 = xv.x + bf2f(rv[0]);
    float s1 = xv.y + bf2f(rv[1]);
    float s2 = xv.z + bf2f(rv[2]);
    float s3 = xv.w + bf2f(rv[3]);

    float sum = s0 + s1 + s2 + s3;
    float sq  = s0*s0 + s1*s1 + s2*s2 + s3*s3;
    #pragma unroll
    for (int off = 32; off > 0; off >>= 1) {
        sum += __shfl_down(sum, off);
        sq  += __shfl_down(sq,  off);
    }
    __shared__ float wsum[4], wsq[4], stat[2];
    const int wid = t >> 6, lane = t & 63;
    if (lane == 0) { wsum[wid] = sum; wsq[wid] = sq; }
    __syncthreads();
    if (t == 0) {
        float S = wsum[0] + wsum[1] + wsum[2] + wsum[3];
        float Q = wsq[0]  + wsq[1]  + wsq[2]  + wsq[3];
        float mean = S * (1.0f / D_);
        float var  = Q * (1.0f / D_) - mean * mean;
        stat[0] = mean;
        stat[1] = rsqrtf(var + 1e-5f);
    }
    __syncthreads();
    const float mean = stat[0], inv = stat[1];
    const float4 gv = ((const float4*)g)[t];
    const float4 bv = ((const float4*)bia)[t];
    us4 ob;
    ob[0] = f2bf((s0 - mean) * inv * gv.x + bv.x);
    ob[1] = f2bf((s1 - mean) * inv * gv.y + bv.y);
    ob[2] = f2bf((s2 - mean) * inv * gv.z + bv.z);
    ob[3] = f2bf((s3 - mean) * inv * gv.w + bv.w);
    *(us4*)(out_bf + (size_t)row * D_ + t * 4) = ob;
}

// ---------------------------------------------------------------------------
// LN2: out_f32 = LayerNorm(Hb_bf16 + Yb_bf16) * g + b
// ---------------------------------------------------------------------------
__global__ __launch_bounds__(256)
void ln_bfbf(const ushort_t* __restrict__ Hb, const ushort_t* __restrict__ Yb,
             const float* __restrict__ g, const float* __restrict__ bia,
             float* __restrict__ outf)
{
    const int row = blockIdx.x;
    const int t   = threadIdx.x;
    const us4 hv = *(const us4*)(Hb + (size_t)row * D_ + t * 4);
    const us4 yv = *(const us4*)(Yb + (size_t)row * D_ + t * 4);
    float s0 = bf2f(hv[0]) + bf2f(yv[0]);
    float s1 = bf2f(hv[1]) + bf2f(yv[1]);
    float s2 = bf2f(hv[2]) + bf2f(yv[2]);
    float s3 = bf2f(hv[3]) + bf2f(yv[3]);

    float sum = s0 + s1 + s2 + s3;
    float sq  = s0*s0 + s1*s1 + s2*s2 + s3*s3;
    #pragma unroll
    for (int off = 32; off > 0; off >>= 1) {
        sum += __shfl_down(sum, off);
        sq  += __shfl_down(sq,  off);
    }
    __shared__ float wsum[4], wsq[4], stat[2];
    const int wid = t >> 6, lane = t & 63;
    if (lane == 0) { wsum[wid] = sum; wsq[wid] = sq; }
    __syncthreads();
    if (t == 0) {
        float S = wsum[0] + wsum[1] + wsum[2] + wsum[3];
        float Q = wsq[0]  + wsq[1]  + wsq[2]  + wsq[3];
        float mean = S * (1.0f / D_);
        float var  = Q * (1.0f / D_) - mean * mean;
        stat[0] = mean;
        stat[1] = rsqrtf(var + 1e-5f);
    }
    __syncthreads();
    const float mean = stat[0], inv = stat[1];
    const float4 gv = ((const float4*)g)[t];
    const float4 bv = ((const float4*)bia)[t];
    float4 o;
    o.x = (s0 - mean) * inv * gv.x + bv.x;
    o.y = (s1 - mean) * inv * gv.y + bv.y;
    o.z = (s2 - mean) * inv * gv.z + bv.z;
    o.w = (s3 - mean) * inv * gv.w + bv.w;
    ((float4*)(outf + (size_t)row * D_))[t] = o;
}

// ---------------------------------------------------------------------------
extern "C" void kernel_launch(void* const* d_in, const int* in_sizes, int n_in,
                              void* d_out, int out_size, void* d_ws, size_t ws_size,
                              hipStream_t stream)
{
    const float* x      = (const float*)d_in[0];
    const float* wq_w   = (const float*)d_in[1];
    const float* wq_b   = (const float*)d_in[2];
    const float* wk_w   = (const float*)d_in[3];
    const float* wk_b   = (const float*)d_in[4];
    const float* wv_w   = (const float*)d_in[5];
    const float* wv_b   = (const float*)d_in[6];
    const float* ln1_g  = (const float*)d_in[7];
    const float* ln1_b  = (const float*)d_in[8];
    const float* lin1_w = (const float*)d_in[9];
    const float* lin1_b = (const float*)d_in[10];
    const float* ln2_g  = (const float*)d_in[11];
    const float* ln2_b  = (const float*)d_in[12];
    float* out = (float*)d_out;

    char* base = (char*)d_ws;
    // ws layout (aliased through the pipeline):
    //   [0   ,16M): x_bf   -> attn_bf (x_bf dead after QKV GEMM)
    //   [16M ,24M): w_bf (wq|wk|wv|lin1)
    //   [24M ,40M): Qbf  -> h_bf   (Qbf dead after attention)
    //   [40M ,56M): Kbf  -> y_bf   (Kbf dead after attention)
    //   [56M ,72M): Vtp
    ushort_t* x_bf    = (ushort_t*)(base);
    ushort_t* attn_bf = (ushort_t*)(base);
    ushort_t* w_bf    = (ushort_t*)(base + 16777216);
    ushort_t* Qbf     = (ushort_t*)(base + 25165824);
    ushort_t* h_bf    = (ushort_t*)(base + 25165824);
    ushort_t* Kbf     = (ushort_t*)(base + 41943040);
    ushort_t* y_bf    = (ushort_t*)(base + 41943040);
    ushort_t* Vtp     = (ushort_t*)(base + 58720256);

    cvt_all<<<dim3(4096 + 4 * 512), 256, 0, stream>>>(
        x, wq_w, wk_w, wv_w, lin1_w, x_bf, w_bf);

    gemm_mfma<<<dim3(M_ / 128, 3072 / 128), 256, 0, stream>>>(
        x_bf, w_bf, wq_b, wk_b, wv_b, nullptr, Qbf, Kbf, Vtp, D_, 0);

    attn_mfma<<<dim3(8, B_ * H_), 256, 0, stream>>>(Qbf, Kbf, Vtp, attn_bf);

    ln_f32bf<<<M_, 256, 0, stream>>>(x, attn_bf, ln1_g, ln1_b, h_bf);

    gemm_mfma<<<dim3(M_ / 128, D_ / 128), 256, 0, stream>>>(
        h_bf, w_bf + 3 * D_ * D_, lin1_b, nullptr, nullptr, y_bf, nullptr, nullptr, nullptr, D_, 1);

    ln_bfbf<<<M_, 256, 0, stream>>>(h_bf, y_bf, ln2_g, ln2_b, out);
}